// Round 2
// baseline (1236.282 us; speedup 1.0000x reference)
//
#include <hip/hip_runtime.h>
#include <hip/hip_bf16.h>

// PhraseDecoderLayer: B=4,S=1024,D=1024,H=16,HD=64,DFF=4096,MEM=256.
// Round 2: dtype-agnostic correctness. Device-side detect of fp32-vs-bf16
// inputs (rope_cos[0..1] bit pattern), canonicalize all inputs to bf16 in ws,
// flag-dependent final store. Sentinel-free causal softmax.

using bf16 = __hip_bfloat16;
typedef __bf16 bf16x8 __attribute__((ext_vector_type(8)));
typedef float f32x4 __attribute__((ext_vector_type(4)));

static constexpr int Bn = 4, Ssz = 1024, Dm = 1024, Hh = 16, HDd = 64, DFFn = 4096, MEMn = 256;

__device__ inline float bf2f(bf16 x) { return __bfloat162float(x); }
__device__ inline bf16 f2bf(float x) { return __float2bfloat16(x); }

// load 8 bf16 (16B aligned) -> 8 fp32
__device__ inline void load8(const bf16* p, float* o) {
  float4 raw = *reinterpret_cast<const float4*>(p);
  const unsigned short* u = reinterpret_cast<const unsigned short*>(&raw);
#pragma unroll
  for (int j = 0; j < 8; ++j) o[j] = __uint_as_float(((unsigned)u[j]) << 16);
}

// ---------------- dtype detect ----------------
// rope_cos row 0 == 1.0f repeated. fp32 -> dword0 = 0x3F800000; bf16 -> 0x3F803F80.
__global__ void detect_kernel(const unsigned* __restrict__ cosw, int* __restrict__ flag) {
  if (threadIdx.x == 0) *flag = (cosw[0] == 0x3F800000u) ? 1 : 0;
}

// ---------------- canonicalize input -> bf16 ----------------
__global__ __launch_bounds__(256) void canon_kernel(const void* __restrict__ src,
                                                    bf16* __restrict__ dst, int n,
                                                    const int* __restrict__ flagp) {
  const int fl = *flagp;  // wave-uniform
  if (fl) {
    const float* s = (const float*)src;
    for (int i = blockIdx.x * 256 + threadIdx.x; i < n; i += gridDim.x * 256)
      dst[i] = f2bf(s[i]);
  } else {
    const bf16* s = (const bf16*)src;
    for (int i = blockIdx.x * 256 + threadIdx.x; i < n; i += gridDim.x * 256)
      dst[i] = s[i];
  }
}

// ---------------- bf16 -> fp32 convert (residual init) ----------------
__global__ __launch_bounds__(256) void to_f32_kernel(const bf16* __restrict__ in,
                                                     float* __restrict__ out, int n) {
  int i = (blockIdx.x * 256 + threadIdx.x) * 8;
  if (i + 8 <= n) {
    float t[8];
    load8(in + i, t);
#pragma unroll
    for (int j = 0; j < 8; ++j) out[i + j] = t[j];
  }
}

// ---------------- LayerNorm (rows of 1024, fp32 in, bf16 out) ----------------
__global__ __launch_bounds__(256) void ln_kernel(const float* __restrict__ x,
                                                 const bf16* __restrict__ g,
                                                 const bf16* __restrict__ bb,
                                                 bf16* __restrict__ y) {
  const int row = blockIdx.x;
  const float* xr = x + (size_t)row * Dm;
  const int i0 = threadIdx.x * 4;
  float4 v = *reinterpret_cast<const float4*>(xr + i0);
  float s = v.x + v.y + v.z + v.w;
  float ss = v.x * v.x + v.y * v.y + v.z * v.z + v.w * v.w;
#pragma unroll
  for (int o = 32; o > 0; o >>= 1) {
    s += __shfl_down(s, o);
    ss += __shfl_down(ss, o);
  }
  __shared__ float shs[4], shss[4];
  const int wave = threadIdx.x >> 6, lane = threadIdx.x & 63;
  if (lane == 0) { shs[wave] = s; shss[wave] = ss; }
  __syncthreads();
  s = shs[0] + shs[1] + shs[2] + shs[3];
  ss = shss[0] + shss[1] + shss[2] + shss[3];
  const float mu = s * (1.0f / Dm);
  const float var = fmaxf(ss * (1.0f / Dm) - mu * mu, 0.0f);
  const float rs = rsqrtf(var + 1e-5f);
  bf16* yr = y + (size_t)row * Dm + i0;
  float vv[4] = {v.x, v.y, v.z, v.w};
#pragma unroll
  for (int j = 0; j < 4; ++j)
    yr[j] = f2bf((vv[j] - mu) * rs * bf2f(g[i0 + j]) + bf2f(bb[i0 + j]));
}

// ---------------- GEMM: C[M,N] = A[M,K] @ W[N,K]^T + bias ----------------
// epi: 0 = store bf16; 1 = gelu->bf16; 2 = residOut_f32 = residIn + acc;
//      3 = final output = residIn + acc, dtype per *flagp (1=f32, 0=bf16)
__global__ __launch_bounds__(256) void gemm_bt(
    const bf16* __restrict__ A, const bf16* __restrict__ W,
    const bf16* __restrict__ bias, bf16* __restrict__ outB, float* __restrict__ outF,
    const float* __restrict__ residIn, float* __restrict__ residOut,
    const int* __restrict__ flagp, int M, int N, int K, int epi) {
  __shared__ bf16 As[64][40];  // +8 pad; row stride 80B keeps 16B alignment
  __shared__ bf16 Ws[64][40];
  const int tid = threadIdx.x;
  const int m0 = blockIdx.x * 64, n0 = blockIdx.y * 64;
  const int wave = tid >> 6, lane = tid & 63;
  const int wm = wave >> 1, wn = wave & 1;
  const int quad = lane >> 4, m16 = lane & 15;
  const int lr = tid >> 2, lc = (tid & 3) * 8;

  f32x4 acc[2][2] = {};

  const bf16* Ap = A + (size_t)(m0 + lr) * K + lc;
  const bf16* Wp = W + (size_t)(n0 + lr) * K + lc;
  for (int k0 = 0; k0 < K; k0 += 32) {
    float4 av = *reinterpret_cast<const float4*>(Ap + k0);
    float4 wv = *reinterpret_cast<const float4*>(Wp + k0);
    *reinterpret_cast<float4*>(&As[lr][lc]) = av;
    *reinterpret_cast<float4*>(&Ws[lr][lc]) = wv;
    __syncthreads();
    bf16x8 aF[2], bF[2];
#pragma unroll
    for (int t = 0; t < 2; ++t) {
      aF[t] = *reinterpret_cast<const bf16x8*>(&As[wm * 32 + t * 16 + m16][quad * 8]);
      bF[t] = *reinterpret_cast<const bf16x8*>(&Ws[wn * 32 + t * 16 + m16][quad * 8]);
    }
#pragma unroll
    for (int mt = 0; mt < 2; ++mt)
#pragma unroll
      for (int nt = 0; nt < 2; ++nt)
        acc[mt][nt] = __builtin_amdgcn_mfma_f32_16x16x32_bf16(aF[mt], bF[nt], acc[mt][nt], 0, 0, 0);
    __syncthreads();
  }
  const int fl = (epi == 3) ? *flagp : 0;
  // C/D layout (m89/m91-verified): col = lane&15, row = quad*4 + reg
#pragma unroll
  for (int mt = 0; mt < 2; ++mt) {
#pragma unroll
    for (int nt = 0; nt < 2; ++nt) {
      const int col = n0 + wn * 32 + nt * 16 + m16;
      const float bv = bf2f(bias[col]);
#pragma unroll
      for (int r = 0; r < 4; ++r) {
        const int row = m0 + wm * 32 + mt * 16 + quad * 4 + r;
        const size_t idx = (size_t)row * N + col;
        float v = acc[mt][nt][r] + bv;
        if (epi == 0) {
          outB[idx] = f2bf(v);
        } else if (epi == 1) {
          outB[idx] = f2bf(0.5f * v * (1.0f + erff(v * 0.70710678118654752f)));
        } else if (epi == 2) {
          residOut[idx] = residIn[idx] + v;
        } else {
          const float rr = residIn[idx] + v;
          if (fl) outF[idx] = rr; else outB[idx] = f2bf(rr);
        }
      }
    }
  }
}

// ---------------- RoPE in-place on qkv buffer [4096, 3072] ----------------
__global__ __launch_bounds__(256) void rope_kernel(bf16* __restrict__ qkv,
                                                   const bf16* __restrict__ cosb,
                                                   const bf16* __restrict__ sinb) {
  const int idx = blockIdx.x * 256 + threadIdx.x;  // over 4096*16*32
  const int i = idx & 31;
  const int h = (idx >> 5) & 15;
  const int r = idx >> 9;  // row 0..4095 = b*1024+s
  const int s = r & (Ssz - 1);
  const float c = bf2f(cosb[s * 32 + i]);
  const float sn = bf2f(sinb[s * 32 + i]);
  bf16* base = qkv + (size_t)r * (3 * Dm) + h * 64 + 2 * i;
  float x0 = bf2f(base[0]), x1 = bf2f(base[1]);
  base[0] = f2bf(x0 * c - x1 * sn);
  base[1] = f2bf(x0 * sn + x1 * c);
  x0 = bf2f(base[Dm]); x1 = bf2f(base[Dm + 1]);
  base[Dm] = f2bf(x0 * c - x1 * sn);
  base[Dm + 1] = f2bf(x0 * sn + x1 * c);
}

// ---------------- Flash attention (vector fp32, sentinel-free masking) -----
// grid: (S/64, H, B). block 256 = 64 q-rows x 4 parts (16 dims each).
__global__ __launch_bounds__(256) void attn_kernel(
    const bf16* __restrict__ Qb, const bf16* __restrict__ Kb, const bf16* __restrict__ Vb,
    bf16* __restrict__ Ob, int qStride, int kvStride, int kvLen, int causal, float scale) {
  __shared__ float Ks[64][64];
  __shared__ float Vs[64][64];
  const int tid = threadIdx.x;
  const int ql = tid >> 2;     // 0..63
  const int part = tid & 3;    // dims part*16..+15
  const int b = blockIdx.z, h = blockIdx.y;
  const int q0 = blockIdx.x * 64;
  const int qrow = q0 + ql;

  float q[16];
  {
    const bf16* qp = Qb + (size_t)(b * Ssz + qrow) * qStride + h * 64 + part * 16;
    load8(qp, q);
    load8(qp + 8, q + 8);
#pragma unroll
    for (int j = 0; j < 16; ++j) q[j] *= scale;
  }
  float o[16];
#pragma unroll
  for (int j = 0; j < 16; ++j) o[j] = 0.0f;
  float m = -30000.0f, l = 0.0f;

  const int nk = causal ? min(kvLen, q0 + 64) : kvLen;
  for (int kt = 0; kt < nk; kt += 64) {
    const int tl = min(64, nk - kt);
    {
      const int kr = tid >> 2, ch = (tid & 3) * 16;
      if (kr < tl) {
        const bf16* kp = Kb + (size_t)(b * kvLen + kt + kr) * kvStride + h * 64 + ch;
        const bf16* vp = Vb + (size_t)(b * kvLen + kt + kr) * kvStride + h * 64 + ch;
        float tk[16], tv[16];
        load8(kp, tk); load8(kp + 8, tk + 8);
        load8(vp, tv); load8(vp + 8, tv + 8);
#pragma unroll
        for (int j = 0; j < 16; ++j) { Ks[kr][ch + j] = tk[j]; Vs[kr][ch + j] = tv[j]; }
      }
    }
    __syncthreads();
    // masked keys are simply not visited (per-thread loop bound)
    const int kmax = causal ? min(tl, qrow - kt + 1) : tl;
    for (int k = 0; k < kmax; ++k) {
      const float4* kr4 = reinterpret_cast<const float4*>(&Ks[k][part * 16]);
      float partial = 0.0f;
#pragma unroll
      for (int c4 = 0; c4 < 4; ++c4) {
        float4 kv = kr4[c4];
        partial += q[c4 * 4 + 0] * kv.x + q[c4 * 4 + 1] * kv.y +
                   q[c4 * 4 + 2] * kv.z + q[c4 * 4 + 3] * kv.w;
      }
      partial += __shfl_xor(partial, 1);
      partial += __shfl_xor(partial, 2);
      const float sc = partial;
      const float mn = fmaxf(m, sc);
      const float corr = __expf(m - mn);
      const float p = __expf(sc - mn);
      l = l * corr + p;
      m = mn;
      const float4* vr4 = reinterpret_cast<const float4*>(&Vs[k][part * 16]);
#pragma unroll
      for (int c4 = 0; c4 < 4; ++c4) {
        float4 vv = vr4[c4];
        o[c4 * 4 + 0] = o[c4 * 4 + 0] * corr + p * vv.x;
        o[c4 * 4 + 1] = o[c4 * 4 + 1] * corr + p * vv.y;
        o[c4 * 4 + 2] = o[c4 * 4 + 2] * corr + p * vv.z;
        o[c4 * 4 + 3] = o[c4 * 4 + 3] * corr + p * vv.w;
      }
    }
    __syncthreads();
  }
  const float inv = 1.0f / l;
  bf16* op = Ob + (size_t)(b * Ssz + qrow) * Dm + h * 64 + part * 16;
#pragma unroll
  for (int j = 0; j < 16; ++j) op[j] = f2bf(o[j] * inv);
}

extern "C" void kernel_launch(void* const* d_in, const int* in_sizes, int n_in,
                              void* d_out, int out_size, void* d_ws, size_t ws_size,
                              hipStream_t stream) {
  char* ws = (char*)d_ws;
  int* flagp   = (int*)ws;                          // [0,1MB) control
  float* resid = (float*)(ws + (1ull << 20));       // 16MB fp32 residual
  bf16* xln    = (bf16*)(ws + (17ull << 20));       // 8MB LN output
  bf16* aout   = (bf16*)(ws + (25ull << 20));       // 8MB attn out
  bf16* big    = (bf16*)(ws + (33ull << 20));       // 32MB: qkv | (qb,kb,vb) | ffn1
  size_t off   = (65ull << 20);                     // canonical bf16 inputs

  // dtype detect from rope_cos (d_in[3]) first dword
  detect_kernel<<<1, 64, 0, stream>>>((const unsigned*)d_in[3], flagp);

  // canonicalize all inputs (skip tgt_mask, index 2) to bf16 copies in ws
  bf16* c[23];
  for (int i = 0; i < 23; ++i) {
    if (i == 2) { c[i] = nullptr; continue; }
    c[i] = (bf16*)(ws + off);
    const int n = in_sizes[i];
    off += ((size_t)n * 2 + 255) & ~(size_t)255;
    int grid = (n + 255) / 256;
    if (grid > 2048) grid = 2048;
    canon_kernel<<<grid, 256, 0, stream>>>(d_in[i], c[i], n, flagp);
  }

  const bf16 *tgt = c[0], *memory = c[1], *rope_cos = c[3], *rope_sin = c[4];
  const bf16 *qkv_w = c[5], *qkv_b = c[6], *out_w = c[7], *out_b = c[8];
  const bf16 *ca_in_w = c[9], *ca_in_b = c[10], *ca_out_w = c[11], *ca_out_b = c[12];
  const bf16 *ffn_w1 = c[13], *ffn_b1 = c[14], *ffn_w2 = c[15], *ffn_b2 = c[16];
  const bf16 *ln1_g = c[17], *ln1_b = c[18], *ln2_g = c[19], *ln2_b = c[20];
  const bf16 *ln3_g = c[21], *ln3_b = c[22];

  bf16* qb = big;                               // 8MB  [33,41)
  bf16* kb = (bf16*)(ws + (41ull << 20));       // 2MB  [41,43)
  bf16* vb = (bf16*)(ws + (43ull << 20));       // 2MB  [43,45)
  bf16* outB = (bf16*)d_out;
  float* outF = (float*)d_out;

  const int ROWS = Bn * Ssz;   // 4096
  const float scale = 0.125f;  // 1/sqrt(64)

  to_f32_kernel<<<(ROWS * Dm) / (256 * 8), 256, 0, stream>>>(tgt, resid, ROWS * Dm);

  // ---- self attention ----
  ln_kernel<<<ROWS, 256, 0, stream>>>(resid, ln1_g, ln1_b, xln);
  gemm_bt<<<dim3(ROWS / 64, (3 * Dm) / 64), 256, 0, stream>>>(
      xln, qkv_w, qkv_b, big, nullptr, nullptr, nullptr, nullptr, ROWS, 3 * Dm, Dm, 0);
  rope_kernel<<<(ROWS * Hh * (HDd / 2)) / 256, 256, 0, stream>>>(big, rope_cos, rope_sin);
  attn_kernel<<<dim3(Ssz / 64, Hh, Bn), 256, 0, stream>>>(
      big, big + Dm, big + 2 * Dm, aout, 3 * Dm, 3 * Dm, Ssz, 1, scale);
  gemm_bt<<<dim3(ROWS / 64, Dm / 64), 256, 0, stream>>>(
      aout, out_w, out_b, nullptr, nullptr, resid, resid, nullptr, ROWS, Dm, Dm, 2);

  // ---- cross attention ----
  ln_kernel<<<ROWS, 256, 0, stream>>>(resid, ln2_g, ln2_b, xln);
  gemm_bt<<<dim3(ROWS / 64, Dm / 64), 256, 0, stream>>>(
      xln, ca_in_w, ca_in_b, qb, nullptr, nullptr, nullptr, nullptr, ROWS, Dm, Dm, 0);
  gemm_bt<<<dim3((Bn * MEMn) / 64, Dm / 64), 256, 0, stream>>>(
      memory, ca_in_w + (size_t)Dm * Dm, ca_in_b + Dm, kb, nullptr, nullptr, nullptr, nullptr,
      Bn * MEMn, Dm, Dm, 0);
  gemm_bt<<<dim3((Bn * MEMn) / 64, Dm / 64), 256, 0, stream>>>(
      memory, ca_in_w + (size_t)2 * Dm * Dm, ca_in_b + 2 * Dm, vb, nullptr, nullptr, nullptr, nullptr,
      Bn * MEMn, Dm, Dm, 0);
  attn_kernel<<<dim3(Ssz / 64, Hh, Bn), 256, 0, stream>>>(
      qb, kb, vb, aout, Dm, Dm, MEMn, 0, scale);
  gemm_bt<<<dim3(ROWS / 64, Dm / 64), 256, 0, stream>>>(
      aout, ca_out_w, ca_out_b, nullptr, nullptr, resid, resid, nullptr, ROWS, Dm, Dm, 2);

  // ---- FFN ----
  ln_kernel<<<ROWS, 256, 0, stream>>>(resid, ln3_g, ln3_b, xln);
  gemm_bt<<<dim3(ROWS / 64, DFFn / 64), 256, 0, stream>>>(
      xln, ffn_w1, ffn_b1, big, nullptr, nullptr, nullptr, nullptr, ROWS, DFFn, Dm, 1);
  gemm_bt<<<dim3(ROWS / 64, Dm / 64), 256, 0, stream>>>(
      big, ffn_w2, ffn_b2, outB, outF, resid, nullptr, flagp, ROWS, Dm, DFFn, 3);
}

// Round 3
// 667.257 us; speedup vs baseline: 1.8528x; 1.8528x over previous
//
#include <hip/hip_runtime.h>
#include <hip/hip_bf16.h>

// PhraseDecoderLayer: B=4,S=1024,D=1024,H=16,HD=64,DFF=4096,MEM=256.
// Round 3: MFMA flash attention (16x16x32 bf16) replaces scalar attn.
// GEMM / LN / canonicalization identical to passing round 2.

using bf16 = __hip_bfloat16;
typedef __bf16 bf16x8 __attribute__((ext_vector_type(8)));
typedef float f32x4 __attribute__((ext_vector_type(4)));

static constexpr int Bn = 4, Ssz = 1024, Dm = 1024, Hh = 16, HDd = 64, DFFn = 4096, MEMn = 256;

__device__ inline float bf2f(bf16 x) { return __bfloat162float(x); }
__device__ inline bf16 f2bf(float x) { return __float2bfloat16(x); }

// load 8 bf16 (16B aligned) -> 8 fp32
__device__ inline void load8(const bf16* p, float* o) {
  float4 raw = *reinterpret_cast<const float4*>(p);
  const unsigned short* u = reinterpret_cast<const unsigned short*>(&raw);
#pragma unroll
  for (int j = 0; j < 8; ++j) o[j] = __uint_as_float(((unsigned)u[j]) << 16);
}

// ---------------- dtype detect ----------------
// rope_cos row 0 == 1.0f repeated. fp32 -> dword0 = 0x3F800000; bf16 -> 0x3F803F80.
__global__ void detect_kernel(const unsigned* __restrict__ cosw, int* __restrict__ flag) {
  if (threadIdx.x == 0) *flag = (cosw[0] == 0x3F800000u) ? 1 : 0;
}

// ---------------- canonicalize input -> bf16 ----------------
__global__ __launch_bounds__(256) void canon_kernel(const void* __restrict__ src,
                                                    bf16* __restrict__ dst, int n,
                                                    const int* __restrict__ flagp) {
  const int fl = *flagp;  // wave-uniform
  if (fl) {
    const float* s = (const float*)src;
    for (int i = blockIdx.x * 256 + threadIdx.x; i < n; i += gridDim.x * 256)
      dst[i] = f2bf(s[i]);
  } else {
    const bf16* s = (const bf16*)src;
    for (int i = blockIdx.x * 256 + threadIdx.x; i < n; i += gridDim.x * 256)
      dst[i] = s[i];
  }
}

// ---------------- bf16 -> fp32 convert (residual init) ----------------
__global__ __launch_bounds__(256) void to_f32_kernel(const bf16* __restrict__ in,
                                                     float* __restrict__ out, int n) {
  int i = (blockIdx.x * 256 + threadIdx.x) * 8;
  if (i + 8 <= n) {
    float t[8];
    load8(in + i, t);
#pragma unroll
    for (int j = 0; j < 8; ++j) out[i + j] = t[j];
  }
}

// ---------------- LayerNorm (rows of 1024, fp32 in, bf16 out) ----------------
__global__ __launch_bounds__(256) void ln_kernel(const float* __restrict__ x,
                                                 const bf16* __restrict__ g,
                                                 const bf16* __restrict__ bb,
                                                 bf16* __restrict__ y) {
  const int row = blockIdx.x;
  const float* xr = x + (size_t)row * Dm;
  const int i0 = threadIdx.x * 4;
  float4 v = *reinterpret_cast<const float4*>(xr + i0);
  float s = v.x + v.y + v.z + v.w;
  float ss = v.x * v.x + v.y * v.y + v.z * v.z + v.w * v.w;
#pragma unroll
  for (int o = 32; o > 0; o >>= 1) {
    s += __shfl_down(s, o);
    ss += __shfl_down(ss, o);
  }
  __shared__ float shs[4], shss[4];
  const int wave = threadIdx.x >> 6, lane = threadIdx.x & 63;
  if (lane == 0) { shs[wave] = s; shss[wave] = ss; }
  __syncthreads();
  s = shs[0] + shs[1] + shs[2] + shs[3];
  ss = shss[0] + shss[1] + shss[2] + shss[3];
  const float mu = s * (1.0f / Dm);
  const float var = fmaxf(ss * (1.0f / Dm) - mu * mu, 0.0f);
  const float rs = rsqrtf(var + 1e-5f);
  bf16* yr = y + (size_t)row * Dm + i0;
  float vv[4] = {v.x, v.y, v.z, v.w};
#pragma unroll
  for (int j = 0; j < 4; ++j)
    yr[j] = f2bf((vv[j] - mu) * rs * bf2f(g[i0 + j]) + bf2f(bb[i0 + j]));
}

// ---------------- GEMM: C[M,N] = A[M,K] @ W[N,K]^T + bias ----------------
// epi: 0 = store bf16; 1 = gelu->bf16; 2 = residOut_f32 = residIn + acc;
//      3 = final output = residIn + acc, dtype per *flagp (1=f32, 0=bf16)
__global__ __launch_bounds__(256) void gemm_bt(
    const bf16* __restrict__ A, const bf16* __restrict__ W,
    const bf16* __restrict__ bias, bf16* __restrict__ outB, float* __restrict__ outF,
    const float* __restrict__ residIn, float* __restrict__ residOut,
    const int* __restrict__ flagp, int M, int N, int K, int epi) {
  __shared__ bf16 As[64][40];  // +8 pad; row stride 80B keeps 16B alignment
  __shared__ bf16 Ws[64][40];
  const int tid = threadIdx.x;
  const int m0 = blockIdx.x * 64, n0 = blockIdx.y * 64;
  const int wave = tid >> 6, lane = tid & 63;
  const int wm = wave >> 1, wn = wave & 1;
  const int quad = lane >> 4, m16 = lane & 15;
  const int lr = tid >> 2, lc = (tid & 3) * 8;

  f32x4 acc[2][2] = {};

  const bf16* Ap = A + (size_t)(m0 + lr) * K + lc;
  const bf16* Wp = W + (size_t)(n0 + lr) * K + lc;
  for (int k0 = 0; k0 < K; k0 += 32) {
    float4 av = *reinterpret_cast<const float4*>(Ap + k0);
    float4 wv = *reinterpret_cast<const float4*>(Wp + k0);
    *reinterpret_cast<float4*>(&As[lr][lc]) = av;
    *reinterpret_cast<float4*>(&Ws[lr][lc]) = wv;
    __syncthreads();
    bf16x8 aF[2], bF[2];
#pragma unroll
    for (int t = 0; t < 2; ++t) {
      aF[t] = *reinterpret_cast<const bf16x8*>(&As[wm * 32 + t * 16 + m16][quad * 8]);
      bF[t] = *reinterpret_cast<const bf16x8*>(&Ws[wn * 32 + t * 16 + m16][quad * 8]);
    }
#pragma unroll
    for (int mt = 0; mt < 2; ++mt)
#pragma unroll
      for (int nt = 0; nt < 2; ++nt)
        acc[mt][nt] = __builtin_amdgcn_mfma_f32_16x16x32_bf16(aF[mt], bF[nt], acc[mt][nt], 0, 0, 0);
    __syncthreads();
  }
  const int fl = (epi == 3) ? *flagp : 0;
  // C/D layout (m89/m91-verified): col = lane&15, row = quad*4 + reg
#pragma unroll
  for (int mt = 0; mt < 2; ++mt) {
#pragma unroll
    for (int nt = 0; nt < 2; ++nt) {
      const int col = n0 + wn * 32 + nt * 16 + m16;
      const float bv = bf2f(bias[col]);
#pragma unroll
      for (int r = 0; r < 4; ++r) {
        const int row = m0 + wm * 32 + mt * 16 + quad * 4 + r;
        const size_t idx = (size_t)row * N + col;
        float v = acc[mt][nt][r] + bv;
        if (epi == 0) {
          outB[idx] = f2bf(v);
        } else if (epi == 1) {
          outB[idx] = f2bf(0.5f * v * (1.0f + erff(v * 0.70710678118654752f)));
        } else if (epi == 2) {
          residOut[idx] = residIn[idx] + v;
        } else {
          const float rr = residIn[idx] + v;
          if (fl) outF[idx] = rr; else outB[idx] = f2bf(rr);
        }
      }
    }
  }
}

// ---------------- RoPE in-place on qkv buffer [4096, 3072] ----------------
__global__ __launch_bounds__(256) void rope_kernel(bf16* __restrict__ qkv,
                                                   const bf16* __restrict__ cosb,
                                                   const bf16* __restrict__ sinb) {
  const int idx = blockIdx.x * 256 + threadIdx.x;  // over 4096*16*32
  const int i = idx & 31;
  const int h = (idx >> 5) & 15;
  const int r = idx >> 9;  // row 0..4095 = b*1024+s
  const int s = r & (Ssz - 1);
  const float c = bf2f(cosb[s * 32 + i]);
  const float sn = bf2f(sinb[s * 32 + i]);
  bf16* base = qkv + (size_t)r * (3 * Dm) + h * 64 + 2 * i;
  float x0 = bf2f(base[0]), x1 = bf2f(base[1]);
  base[0] = f2bf(x0 * c - x1 * sn);
  base[1] = f2bf(x0 * sn + x1 * c);
  x0 = bf2f(base[Dm]); x1 = bf2f(base[Dm + 1]);
  base[Dm] = f2bf(x0 * c - x1 * sn);
  base[Dm + 1] = f2bf(x0 * sn + x1 * c);
}

// ---------------- MFMA flash attention ----------------
// grid: (S/64, H, B), block 256 (4 waves). Wave w owns q rows q0+16w..+15.
// Q/K rows: (b*len + i)*stride + h*64. Out rows: stride Dm.
// S-tile: C-layout row(q)=quad*4+r, col(k)=m16. P LDS round-trip to A-layout.
// V staged transposed (Vt[hd][k]) so PV B-frags are contiguous b128 reads.
__global__ __launch_bounds__(256) void attn_mfma(
    const bf16* __restrict__ Qb, const bf16* __restrict__ Kb, const bf16* __restrict__ Vb,
    bf16* __restrict__ Ob, int qStride, int kvStride, int kvLen, int causal, float scale) {
  __shared__ bf16 Ks[64][72];
  __shared__ bf16 Vt[64][72];  // Vt[hd][k]
  __shared__ bf16 Ps[64][72];  // Q staging, then P tiles (wave-private rows)
  const int tid = threadIdx.x;
  const int wave = tid >> 6, lane = tid & 63;
  const int quad = lane >> 4, m16 = lane & 15;
  const int b = blockIdx.z, h = blockIdx.y;
  const int q0 = blockIdx.x * 64;
  const int sr = tid >> 2, sc = (tid & 3) * 16;  // staging row/col (wave w -> rows 16w..16w+15)

  // ---- stage Q tile (64 x 64) into Ps, pull A-frags ----
  {
    const bf16* qp = Qb + (size_t)(b * Ssz + q0 + sr) * qStride + h * 64 + sc;
    float4 a = reinterpret_cast<const float4*>(qp)[0];
    float4 bb2 = reinterpret_cast<const float4*>(qp)[1];
    *reinterpret_cast<float4*>(&Ps[sr][sc]) = a;
    *reinterpret_cast<float4*>(&Ps[sr][sc + 8]) = bb2;
  }
  __syncthreads();
  bf16x8 qf[2];
  qf[0] = *reinterpret_cast<const bf16x8*>(&Ps[wave * 16 + m16][quad * 8]);
  qf[1] = *reinterpret_cast<const bf16x8*>(&Ps[wave * 16 + m16][32 + quad * 8]);

  f32x4 oacc[4] = {};          // col hd = nt*16+m16, row q = quad*4+r (wave-local)
  float mrow[4], lrow[4];
#pragma unroll
  for (int r = 0; r < 4; ++r) { mrow[r] = -30000.0f; lrow[r] = 0.0f; }

  const int nk = causal ? (q0 + 64) : kvLen;
  for (int kt = 0; kt < nk; kt += 64) {
    // ---- stage K (row-major) and V (transposed) ----
    {
      const bf16* kp = Kb + (size_t)(b * kvLen + kt + sr) * kvStride + h * 64 + sc;
      float4 k1 = reinterpret_cast<const float4*>(kp)[0];
      float4 k2 = reinterpret_cast<const float4*>(kp)[1];
      *reinterpret_cast<float4*>(&Ks[sr][sc]) = k1;
      *reinterpret_cast<float4*>(&Ks[sr][sc + 8]) = k2;
      const bf16* vp = Vb + (size_t)(b * kvLen + kt + sr) * kvStride + h * 64 + sc;
      float4 v1 = reinterpret_cast<const float4*>(vp)[0];
      float4 v2 = reinterpret_cast<const float4*>(vp)[1];
      const bf16* tv1 = reinterpret_cast<const bf16*>(&v1);
      const bf16* tv2 = reinterpret_cast<const bf16*>(&v2);
#pragma unroll
      for (int j = 0; j < 8; ++j) {
        Vt[sc + j][sr] = tv1[j];
        Vt[sc + 8 + j][sr] = tv2[j];
      }
    }
    __syncthreads();

    // ---- S = scale * Q K^T  (wave's 16 q rows x 64 keys) ----
    f32x4 sacc[4] = {};
#pragma unroll
    for (int nt = 0; nt < 4; ++nt) {
      bf16x8 kf0 = *reinterpret_cast<const bf16x8*>(&Ks[nt * 16 + m16][quad * 8]);
      bf16x8 kf1 = *reinterpret_cast<const bf16x8*>(&Ks[nt * 16 + m16][32 + quad * 8]);
      sacc[nt] = __builtin_amdgcn_mfma_f32_16x16x32_bf16(qf[0], kf0, sacc[nt], 0, 0, 0);
      sacc[nt] = __builtin_amdgcn_mfma_f32_16x16x32_bf16(qf[1], kf1, sacc[nt], 0, 0, 0);
    }
    const bool dmask = (causal != 0) && (kt == q0);  // only diagonal tile masks
#pragma unroll
    for (int nt = 0; nt < 4; ++nt) {
#pragma unroll
      for (int r = 0; r < 4; ++r) {
        float s = sacc[nt][r] * scale;
        if (dmask && (nt * 16 + m16 > wave * 16 + quad * 4 + r)) s = -30000.0f;
        sacc[nt][r] = s;
      }
    }

    // ---- online softmax per row (redundant across quad-group of 16 lanes) ----
#pragma unroll
    for (int r = 0; r < 4; ++r) {
      float mx = fmaxf(fmaxf(sacc[0][r], sacc[1][r]), fmaxf(sacc[2][r], sacc[3][r]));
#pragma unroll
      for (int off = 1; off < 16; off <<= 1) mx = fmaxf(mx, __shfl_xor(mx, off));
      const float mn = fmaxf(mrow[r], mx);
      const float corr = __expf(mrow[r] - mn);
      mrow[r] = mn;
      float psum = 0.0f;
#pragma unroll
      for (int nt = 0; nt < 4; ++nt) {
        const float p = __expf(sacc[nt][r] - mn);
        sacc[nt][r] = p;
        psum += p;
      }
#pragma unroll
      for (int off = 1; off < 16; off <<= 1) psum += __shfl_xor(psum, off);
      lrow[r] = lrow[r] * corr + psum;
#pragma unroll
      for (int nt = 0; nt < 4; ++nt) oacc[nt][r] *= corr;
      // write P row to wave-private LDS rows (C-layout -> memory)
#pragma unroll
      for (int nt = 0; nt < 4; ++nt)
        Ps[wave * 16 + quad * 4 + r][nt * 16 + m16] = f2bf(sacc[nt][r]);
    }
    // wave-internal LDS write->read (wave-synchronous, no barrier needed)
    bf16x8 pf0 = *reinterpret_cast<const bf16x8*>(&Ps[wave * 16 + m16][quad * 8]);
    bf16x8 pf1 = *reinterpret_cast<const bf16x8*>(&Ps[wave * 16 + m16][32 + quad * 8]);
#pragma unroll
    for (int nt = 0; nt < 4; ++nt) {
      bf16x8 vf0 = *reinterpret_cast<const bf16x8*>(&Vt[nt * 16 + m16][quad * 8]);
      bf16x8 vf1 = *reinterpret_cast<const bf16x8*>(&Vt[nt * 16 + m16][32 + quad * 8]);
      oacc[nt] = __builtin_amdgcn_mfma_f32_16x16x32_bf16(pf0, vf0, oacc[nt], 0, 0, 0);
      oacc[nt] = __builtin_amdgcn_mfma_f32_16x16x32_bf16(pf1, vf1, oacc[nt], 0, 0, 0);
    }
    __syncthreads();  // all waves done with Ks/Vt before next staging
  }

  // ---- epilogue: O /= l, store ----
  float inv[4];
#pragma unroll
  for (int r = 0; r < 4; ++r) inv[r] = 1.0f / lrow[r];
#pragma unroll
  for (int r = 0; r < 4; ++r) {
    bf16* op = Ob + (size_t)(b * Ssz + q0 + wave * 16 + quad * 4 + r) * Dm + h * 64 + m16;
#pragma unroll
    for (int nt = 0; nt < 4; ++nt) op[nt * 16] = f2bf(oacc[nt][r] * inv[r]);
  }
}

extern "C" void kernel_launch(void* const* d_in, const int* in_sizes, int n_in,
                              void* d_out, int out_size, void* d_ws, size_t ws_size,
                              hipStream_t stream) {
  char* ws = (char*)d_ws;
  int* flagp   = (int*)ws;                          // [0,1MB) control
  float* resid = (float*)(ws + (1ull << 20));       // 16MB fp32 residual
  bf16* xln    = (bf16*)(ws + (17ull << 20));       // 8MB LN output
  bf16* aout   = (bf16*)(ws + (25ull << 20));       // 8MB attn out
  bf16* big    = (bf16*)(ws + (33ull << 20));       // 32MB: qkv | (qb,kb,vb) | ffn1
  size_t off   = (65ull << 20);                     // canonical bf16 inputs

  // dtype detect from rope_cos (d_in[3]) first dword
  detect_kernel<<<1, 64, 0, stream>>>((const unsigned*)d_in[3], flagp);

  // canonicalize all inputs (skip tgt_mask, index 2) to bf16 copies in ws
  bf16* c[23];
  for (int i = 0; i < 23; ++i) {
    if (i == 2) { c[i] = nullptr; continue; }
    c[i] = (bf16*)(ws + off);
    const int n = in_sizes[i];
    off += ((size_t)n * 2 + 255) & ~(size_t)255;
    int grid = (n + 255) / 256;
    if (grid > 2048) grid = 2048;
    canon_kernel<<<grid, 256, 0, stream>>>(d_in[i], c[i], n, flagp);
  }

  const bf16 *tgt = c[0], *memory = c[1], *rope_cos = c[3], *rope_sin = c[4];
  const bf16 *qkv_w = c[5], *qkv_b = c[6], *out_w = c[7], *out_b = c[8];
  const bf16 *ca_in_w = c[9], *ca_in_b = c[10], *ca_out_w = c[11], *ca_out_b = c[12];
  const bf16 *ffn_w1 = c[13], *ffn_b1 = c[14], *ffn_w2 = c[15], *ffn_b2 = c[16];
  const bf16 *ln1_g = c[17], *ln1_b = c[18], *ln2_g = c[19], *ln2_b = c[20];
  const bf16 *ln3_g = c[21], *ln3_b = c[22];

  bf16* qb = big;                               // 8MB  [33,41)
  bf16* kb = (bf16*)(ws + (41ull << 20));       // 2MB  [41,43)
  bf16* vb = (bf16*)(ws + (43ull << 20));       // 2MB  [43,45)
  bf16* outB = (bf16*)d_out;
  float* outF = (float*)d_out;

  const int ROWS = Bn * Ssz;   // 4096
  const float scale = 0.125f;  // 1/sqrt(64)

  to_f32_kernel<<<(ROWS * Dm) / (256 * 8), 256, 0, stream>>>(tgt, resid, ROWS * Dm);

  // ---- self attention ----
  ln_kernel<<<ROWS, 256, 0, stream>>>(resid, ln1_g, ln1_b, xln);
  gemm_bt<<<dim3(ROWS / 64, (3 * Dm) / 64), 256, 0, stream>>>(
      xln, qkv_w, qkv_b, big, nullptr, nullptr, nullptr, nullptr, ROWS, 3 * Dm, Dm, 0);
  rope_kernel<<<(ROWS * Hh * (HDd / 2)) / 256, 256, 0, stream>>>(big, rope_cos, rope_sin);
  attn_mfma<<<dim3(Ssz / 64, Hh, Bn), 256, 0, stream>>>(
      big, big + Dm, big + 2 * Dm, aout, 3 * Dm, 3 * Dm, Ssz, 1, scale);
  gemm_bt<<<dim3(ROWS / 64, Dm / 64), 256, 0, stream>>>(
      aout, out_w, out_b, nullptr, nullptr, resid, resid, nullptr, ROWS, Dm, Dm, 2);

  // ---- cross attention ----
  ln_kernel<<<ROWS, 256, 0, stream>>>(resid, ln2_g, ln2_b, xln);
  gemm_bt<<<dim3(ROWS / 64, Dm / 64), 256, 0, stream>>>(
      xln, ca_in_w, ca_in_b, qb, nullptr, nullptr, nullptr, nullptr, ROWS, Dm, Dm, 0);
  gemm_bt<<<dim3((Bn * MEMn) / 64, Dm / 64), 256, 0, stream>>>(
      memory, ca_in_w + (size_t)Dm * Dm, ca_in_b + Dm, kb, nullptr, nullptr, nullptr, nullptr,
      Bn * MEMn, Dm, Dm, 0);
  gemm_bt<<<dim3((Bn * MEMn) / 64, Dm / 64), 256, 0, stream>>>(
      memory, ca_in_w + (size_t)2 * Dm * Dm, ca_in_b + 2 * Dm, vb, nullptr, nullptr, nullptr, nullptr,
      Bn * MEMn, Dm, Dm, 0);
  attn_mfma<<<dim3(Ssz / 64, Hh, Bn), 256, 0, stream>>>(
      qb, kb, vb, aout, Dm, Dm, MEMn, 0, scale);
  gemm_bt<<<dim3(ROWS / 64, Dm / 64), 256, 0, stream>>>(
      aout, ca_out_w, ca_out_b, nullptr, nullptr, resid, resid, nullptr, ROWS, Dm, Dm, 2);

  // ---- FFN ----
  ln_kernel<<<ROWS, 256, 0, stream>>>(resid, ln3_g, ln3_b, xln);
  gemm_bt<<<dim3(ROWS / 64, DFFn / 64), 256, 0, stream>>>(
      xln, ffn_w1, ffn_b1, big, nullptr, nullptr, nullptr, nullptr, ROWS, DFFn, Dm, 1);
  gemm_bt<<<dim3(ROWS / 64, Dm / 64), 256, 0, stream>>>(
      big, ffn_w2, ffn_b2, outB, outF, resid, nullptr, flagp, ROWS, Dm, DFFn, 3);
}

// Round 4
// 660.516 us; speedup vs baseline: 1.8717x; 1.0102x over previous
//
#include <hip/hip_runtime.h>
#include <hip/hip_bf16.h>

// PhraseDecoderLayer: B=4,S=1024,D=1024,H=16,HD=64,DFF=4096,MEM=256.
// Round 4: m97-structure 128x128 GEMM with global_load_lds(16B) for all
// M=4096 GEMMs; fused single-kernel input canonicalization.
// Attention (MFMA flash) and kv GEMMs unchanged from passing round 3.

using bf16 = __hip_bfloat16;
typedef __bf16 bf16x8 __attribute__((ext_vector_type(8)));
typedef float f32x4 __attribute__((ext_vector_type(4)));
typedef __attribute__((address_space(3))) void lds_void;
typedef const __attribute__((address_space(1))) void glob_void;

static constexpr int Bn = 4, Ssz = 1024, Dm = 1024, Hh = 16, HDd = 64, DFFn = 4096, MEMn = 256;

__device__ inline float bf2f(bf16 x) { return __bfloat162float(x); }
__device__ inline bf16 f2bf(float x) { return __float2bfloat16(x); }

// load 8 bf16 (16B aligned) -> 8 fp32
__device__ inline void load8(const bf16* p, float* o) {
  float4 raw = *reinterpret_cast<const float4*>(p);
  const unsigned short* u = reinterpret_cast<const unsigned short*>(&raw);
#pragma unroll
  for (int j = 0; j < 8; ++j) o[j] = __uint_as_float(((unsigned)u[j]) << 16);
}

// ---------------- dtype detect ----------------
// rope_cos row 0 == 1.0f repeated. fp32 -> dword0 = 0x3F800000; bf16 -> 0x3F803F80.
__global__ void detect_kernel(const unsigned* __restrict__ cosw, int* __restrict__ flag) {
  if (threadIdx.x == 0) *flag = (cosw[0] == 0x3F800000u) ? 1 : 0;
}

// ---------------- fused canonicalize: all inputs -> bf16 ----------------
struct CanonArgs {
  const void* src[23];
  void* dst[23];
  int n[23];  // element count (0 = skip); all counts divisible by 4
};
__global__ __launch_bounds__(256) void canon_all(CanonArgs a, const int* __restrict__ flagp) {
  const int seg = blockIdx.y;
  const int n4 = a.n[seg] >> 2;
  if (n4 == 0) return;
  const int fl = *flagp;  // wave-uniform
  if (fl) {
    const float4* s = (const float4*)a.src[seg];
    bf16* d = (bf16*)a.dst[seg];
    for (int i = blockIdx.x * 256 + threadIdx.x; i < n4; i += gridDim.x * 256) {
      float4 v = s[i];
      bf16 t[4] = {f2bf(v.x), f2bf(v.y), f2bf(v.z), f2bf(v.w)};
      *reinterpret_cast<unsigned long long*>(d + i * 4) =
          *reinterpret_cast<unsigned long long*>(t);
    }
  } else {
    const unsigned long long* s = (const unsigned long long*)a.src[seg];
    unsigned long long* d = (unsigned long long*)a.dst[seg];
    for (int i = blockIdx.x * 256 + threadIdx.x; i < n4; i += gridDim.x * 256)
      d[i] = s[i];
  }
}

// ---------------- bf16 -> fp32 convert (residual init) ----------------
__global__ __launch_bounds__(256) void to_f32_kernel(const bf16* __restrict__ in,
                                                     float* __restrict__ out, int n) {
  int i = (blockIdx.x * 256 + threadIdx.x) * 8;
  if (i + 8 <= n) {
    float t[8];
    load8(in + i, t);
#pragma unroll
    for (int j = 0; j < 8; ++j) out[i + j] = t[j];
  }
}

// ---------------- LayerNorm (rows of 1024, fp32 in, bf16 out) ----------------
__global__ __launch_bounds__(256) void ln_kernel(const float* __restrict__ x,
                                                 const bf16* __restrict__ g,
                                                 const bf16* __restrict__ bb,
                                                 bf16* __restrict__ y) {
  const int row = blockIdx.x;
  const float* xr = x + (size_t)row * Dm;
  const int i0 = threadIdx.x * 4;
  float4 v = *reinterpret_cast<const float4*>(xr + i0);
  float s = v.x + v.y + v.z + v.w;
  float ss = v.x * v.x + v.y * v.y + v.z * v.z + v.w * v.w;
#pragma unroll
  for (int o = 32; o > 0; o >>= 1) {
    s += __shfl_down(s, o);
    ss += __shfl_down(ss, o);
  }
  __shared__ float shs[4], shss[4];
  const int wave = threadIdx.x >> 6, lane = threadIdx.x & 63;
  if (lane == 0) { shs[wave] = s; shss[wave] = ss; }
  __syncthreads();
  s = shs[0] + shs[1] + shs[2] + shs[3];
  ss = shss[0] + shss[1] + shss[2] + shss[3];
  const float mu = s * (1.0f / Dm);
  const float var = fmaxf(ss * (1.0f / Dm) - mu * mu, 0.0f);
  const float rs = rsqrtf(var + 1e-5f);
  bf16* yr = y + (size_t)row * Dm + i0;
  float vv[4] = {v.x, v.y, v.z, v.w};
#pragma unroll
  for (int j = 0; j < 4; ++j)
    yr[j] = f2bf((vv[j] - mu) * rs * bf2f(g[i0 + j]) + bf2f(bb[i0 + j]));
}

// ---------------- GEMM 64x64 (round-2 verified; used for M=1024 kv) --------
__global__ __launch_bounds__(256) void gemm_bt(
    const bf16* __restrict__ A, const bf16* __restrict__ W,
    const bf16* __restrict__ bias, bf16* __restrict__ outB, float* __restrict__ outF,
    const float* __restrict__ residIn, float* __restrict__ residOut,
    const int* __restrict__ flagp, int M, int N, int K, int epi) {
  __shared__ bf16 As[64][40];
  __shared__ bf16 Ws[64][40];
  const int tid = threadIdx.x;
  const int m0 = blockIdx.x * 64, n0 = blockIdx.y * 64;
  const int wave = tid >> 6, lane = tid & 63;
  const int wm = wave >> 1, wn = wave & 1;
  const int quad = lane >> 4, m16 = lane & 15;
  const int lr = tid >> 2, lc = (tid & 3) * 8;

  f32x4 acc[2][2] = {};

  const bf16* Ap = A + (size_t)(m0 + lr) * K + lc;
  const bf16* Wp = W + (size_t)(n0 + lr) * K + lc;
  for (int k0 = 0; k0 < K; k0 += 32) {
    float4 av = *reinterpret_cast<const float4*>(Ap + k0);
    float4 wv = *reinterpret_cast<const float4*>(Wp + k0);
    *reinterpret_cast<float4*>(&As[lr][lc]) = av;
    *reinterpret_cast<float4*>(&Ws[lr][lc]) = wv;
    __syncthreads();
    bf16x8 aF[2], bF[2];
#pragma unroll
    for (int t = 0; t < 2; ++t) {
      aF[t] = *reinterpret_cast<const bf16x8*>(&As[wm * 32 + t * 16 + m16][quad * 8]);
      bF[t] = *reinterpret_cast<const bf16x8*>(&Ws[wn * 32 + t * 16 + m16][quad * 8]);
    }
#pragma unroll
    for (int mt = 0; mt < 2; ++mt)
#pragma unroll
      for (int nt = 0; nt < 2; ++nt)
        acc[mt][nt] = __builtin_amdgcn_mfma_f32_16x16x32_bf16(aF[mt], bF[nt], acc[mt][nt], 0, 0, 0);
    __syncthreads();
  }
  const int fl = (epi == 3) ? *flagp : 0;
#pragma unroll
  for (int mt = 0; mt < 2; ++mt) {
#pragma unroll
    for (int nt = 0; nt < 2; ++nt) {
      const int col = n0 + wn * 32 + nt * 16 + m16;
      const float bv = bf2f(bias[col]);
#pragma unroll
      for (int r = 0; r < 4; ++r) {
        const int row = m0 + wm * 32 + mt * 16 + quad * 4 + r;
        const size_t idx = (size_t)row * N + col;
        float v = acc[mt][nt][r] + bv;
        if (epi == 0) {
          outB[idx] = f2bf(v);
        } else if (epi == 1) {
          outB[idx] = f2bf(0.5f * v * (1.0f + erff(v * 0.70710678118654752f)));
        } else if (epi == 2) {
          residOut[idx] = residIn[idx] + v;
        } else {
          const float rr = residIn[idx] + v;
          if (fl) outF[idx] = rr; else outB[idx] = f2bf(rr);
        }
      }
    }
  }
}

// ---------------- GEMM 128x128 (m97 structure): C = A @ W^T + bias ----------
// BK=32, unpadded LDS tiles, global_load_lds width=16 staging.
// Staging map (wave-uniform LDS base): wave w, round r covers rows
// (r*4+w)*16 .. +15; lane l -> row base + l/4, col (l&3)*8.
// epi as gemm_bt.
__global__ __launch_bounds__(256) void gemm128(
    const bf16* __restrict__ A, const bf16* __restrict__ W,
    const bf16* __restrict__ bias, bf16* __restrict__ outB, float* __restrict__ outF,
    const float* __restrict__ residIn, float* __restrict__ residOut,
    const int* __restrict__ flagp, int M, int N, int K, int epi) {
  __shared__ bf16 As[128][32];
  __shared__ bf16 Ws[128][32];
  const int tid = threadIdx.x;
  const int wave = tid >> 6, lane = tid & 63;
  const int wm = wave >> 1, wn = wave & 1;
  const int quad = lane >> 4, m16 = lane & 15;
  const int m0 = blockIdx.x * 128, n0 = blockIdx.y * 128;

  const int srow = wave * 16 + (lane >> 2);  // round-0 row this lane sources
  const int scol = (lane & 3) * 8;
  const bf16* Ag = A + (size_t)(m0 + srow) * K + scol;
  const bf16* Wg = W + (size_t)(n0 + srow) * K + scol;

  f32x4 acc[4][4] = {};

  for (int k0 = 0; k0 < K; k0 += 32) {
#pragma unroll
    for (int r = 0; r < 2; ++r) {
      __builtin_amdgcn_global_load_lds(
          (glob_void*)(Ag + (size_t)(r * 64) * K + k0),
          (lds_void*)&As[(r * 4 + wave) * 16][0], 16, 0, 0);
      __builtin_amdgcn_global_load_lds(
          (glob_void*)(Wg + (size_t)(r * 64) * K + k0),
          (lds_void*)&Ws[(r * 4 + wave) * 16][0], 16, 0, 0);
    }
    __syncthreads();  // drains vmcnt before barrier
    bf16x8 aF[4], bF[4];
#pragma unroll
    for (int t = 0; t < 4; ++t) {
      aF[t] = *reinterpret_cast<const bf16x8*>(&As[wm * 64 + t * 16 + m16][quad * 8]);
      bF[t] = *reinterpret_cast<const bf16x8*>(&Ws[wn * 64 + t * 16 + m16][quad * 8]);
    }
#pragma unroll
    for (int mt = 0; mt < 4; ++mt)
#pragma unroll
      for (int nt = 0; nt < 4; ++nt)
        acc[mt][nt] = __builtin_amdgcn_mfma_f32_16x16x32_bf16(aF[mt], bF[nt], acc[mt][nt], 0, 0, 0);
    __syncthreads();
  }
  const int fl = (epi == 3) ? *flagp : 0;
  // C/D layout: col = lane&15, row = quad*4 + reg
#pragma unroll
  for (int mt = 0; mt < 4; ++mt) {
#pragma unroll
    for (int nt = 0; nt < 4; ++nt) {
      const int col = n0 + wn * 64 + nt * 16 + m16;
      const float bv = bf2f(bias[col]);
#pragma unroll
      for (int r = 0; r < 4; ++r) {
        const int row = m0 + wm * 64 + mt * 16 + quad * 4 + r;
        const size_t idx = (size_t)row * N + col;
        float v = acc[mt][nt][r] + bv;
        if (epi == 0) {
          outB[idx] = f2bf(v);
        } else if (epi == 1) {
          outB[idx] = f2bf(0.5f * v * (1.0f + erff(v * 0.70710678118654752f)));
        } else if (epi == 2) {
          residOut[idx] = residIn[idx] + v;
        } else {
          const float rr = residIn[idx] + v;
          if (fl) outF[idx] = rr; else outB[idx] = f2bf(rr);
        }
      }
    }
  }
}

// ---------------- RoPE in-place on qkv buffer [4096, 3072] ----------------
__global__ __launch_bounds__(256) void rope_kernel(bf16* __restrict__ qkv,
                                                   const bf16* __restrict__ cosb,
                                                   const bf16* __restrict__ sinb) {
  const int idx = blockIdx.x * 256 + threadIdx.x;  // over 4096*16*32
  const int i = idx & 31;
  const int h = (idx >> 5) & 15;
  const int r = idx >> 9;  // row 0..4095 = b*1024+s
  const int s = r & (Ssz - 1);
  const float c = bf2f(cosb[s * 32 + i]);
  const float sn = bf2f(sinb[s * 32 + i]);
  bf16* base = qkv + (size_t)r * (3 * Dm) + h * 64 + 2 * i;
  float x0 = bf2f(base[0]), x1 = bf2f(base[1]);
  base[0] = f2bf(x0 * c - x1 * sn);
  base[1] = f2bf(x0 * sn + x1 * c);
  x0 = bf2f(base[Dm]); x1 = bf2f(base[Dm + 1]);
  base[Dm] = f2bf(x0 * c - x1 * sn);
  base[Dm + 1] = f2bf(x0 * sn + x1 * c);
}

// ---------------- MFMA flash attention (round-3 verified) ----------------
__global__ __launch_bounds__(256) void attn_mfma(
    const bf16* __restrict__ Qb, const bf16* __restrict__ Kb, const bf16* __restrict__ Vb,
    bf16* __restrict__ Ob, int qStride, int kvStride, int kvLen, int causal, float scale) {
  __shared__ bf16 Ks[64][72];
  __shared__ bf16 Vt[64][72];
  __shared__ bf16 Ps[64][72];
  const int tid = threadIdx.x;
  const int wave = tid >> 6, lane = tid & 63;
  const int quad = lane >> 4, m16 = lane & 15;
  const int b = blockIdx.z, h = blockIdx.y;
  const int q0 = blockIdx.x * 64;
  const int sr = tid >> 2, sc = (tid & 3) * 16;

  {
    const bf16* qp = Qb + (size_t)(b * Ssz + q0 + sr) * qStride + h * 64 + sc;
    float4 a = reinterpret_cast<const float4*>(qp)[0];
    float4 bb2 = reinterpret_cast<const float4*>(qp)[1];
    *reinterpret_cast<float4*>(&Ps[sr][sc]) = a;
    *reinterpret_cast<float4*>(&Ps[sr][sc + 8]) = bb2;
  }
  __syncthreads();
  bf16x8 qf[2];
  qf[0] = *reinterpret_cast<const bf16x8*>(&Ps[wave * 16 + m16][quad * 8]);
  qf[1] = *reinterpret_cast<const bf16x8*>(&Ps[wave * 16 + m16][32 + quad * 8]);

  f32x4 oacc[4] = {};
  float mrow[4], lrow[4];
#pragma unroll
  for (int r = 0; r < 4; ++r) { mrow[r] = -30000.0f; lrow[r] = 0.0f; }

  const int nk = causal ? (q0 + 64) : kvLen;
  for (int kt = 0; kt < nk; kt += 64) {
    {
      const bf16* kp = Kb + (size_t)(b * kvLen + kt + sr) * kvStride + h * 64 + sc;
      float4 k1 = reinterpret_cast<const float4*>(kp)[0];
      float4 k2 = reinterpret_cast<const float4*>(kp)[1];
      *reinterpret_cast<float4*>(&Ks[sr][sc]) = k1;
      *reinterpret_cast<float4*>(&Ks[sr][sc + 8]) = k2;
      const bf16* vp = Vb + (size_t)(b * kvLen + kt + sr) * kvStride + h * 64 + sc;
      float4 v1 = reinterpret_cast<const float4*>(vp)[0];
      float4 v2 = reinterpret_cast<const float4*>(vp)[1];
      const bf16* tv1 = reinterpret_cast<const bf16*>(&v1);
      const bf16* tv2 = reinterpret_cast<const bf16*>(&v2);
#pragma unroll
      for (int j = 0; j < 8; ++j) {
        Vt[sc + j][sr] = tv1[j];
        Vt[sc + 8 + j][sr] = tv2[j];
      }
    }
    __syncthreads();

    f32x4 sacc[4] = {};
#pragma unroll
    for (int nt = 0; nt < 4; ++nt) {
      bf16x8 kf0 = *reinterpret_cast<const bf16x8*>(&Ks[nt * 16 + m16][quad * 8]);
      bf16x8 kf1 = *reinterpret_cast<const bf16x8*>(&Ks[nt * 16 + m16][32 + quad * 8]);
      sacc[nt] = __builtin_amdgcn_mfma_f32_16x16x32_bf16(qf[0], kf0, sacc[nt], 0, 0, 0);
      sacc[nt] = __builtin_amdgcn_mfma_f32_16x16x32_bf16(qf[1], kf1, sacc[nt], 0, 0, 0);
    }
    const bool dmask = (causal != 0) && (kt == q0);
#pragma unroll
    for (int nt = 0; nt < 4; ++nt) {
#pragma unroll
      for (int r = 0; r < 4; ++r) {
        float s = sacc[nt][r] * scale;
        if (dmask && (nt * 16 + m16 > wave * 16 + quad * 4 + r)) s = -30000.0f;
        sacc[nt][r] = s;
      }
    }

#pragma unroll
    for (int r = 0; r < 4; ++r) {
      float mx = fmaxf(fmaxf(sacc[0][r], sacc[1][r]), fmaxf(sacc[2][r], sacc[3][r]));
#pragma unroll
      for (int off = 1; off < 16; off <<= 1) mx = fmaxf(mx, __shfl_xor(mx, off));
      const float mn = fmaxf(mrow[r], mx);
      const float corr = __expf(mrow[r] - mn);
      mrow[r] = mn;
      float psum = 0.0f;
#pragma unroll
      for (int nt = 0; nt < 4; ++nt) {
        const float p = __expf(sacc[nt][r] - mn);
        sacc[nt][r] = p;
        psum += p;
      }
#pragma unroll
      for (int off = 1; off < 16; off <<= 1) psum += __shfl_xor(psum, off);
      lrow[r] = lrow[r] * corr + psum;
#pragma unroll
      for (int nt = 0; nt < 4; ++nt) oacc[nt][r] *= corr;
#pragma unroll
      for (int nt = 0; nt < 4; ++nt)
        Ps[wave * 16 + quad * 4 + r][nt * 16 + m16] = f2bf(sacc[nt][r]);
    }
    bf16x8 pf0 = *reinterpret_cast<const bf16x8*>(&Ps[wave * 16 + m16][quad * 8]);
    bf16x8 pf1 = *reinterpret_cast<const bf16x8*>(&Ps[wave * 16 + m16][32 + quad * 8]);
#pragma unroll
    for (int nt = 0; nt < 4; ++nt) {
      bf16x8 vf0 = *reinterpret_cast<const bf16x8*>(&Vt[nt * 16 + m16][quad * 8]);
      bf16x8 vf1 = *reinterpret_cast<const bf16x8*>(&Vt[nt * 16 + m16][32 + quad * 8]);
      oacc[nt] = __builtin_amdgcn_mfma_f32_16x16x32_bf16(pf0, vf0, oacc[nt], 0, 0, 0);
      oacc[nt] = __builtin_amdgcn_mfma_f32_16x16x32_bf16(pf1, vf1, oacc[nt], 0, 0, 0);
    }
    __syncthreads();
  }

  float inv[4];
#pragma unroll
  for (int r = 0; r < 4; ++r) inv[r] = 1.0f / lrow[r];
#pragma unroll
  for (int r = 0; r < 4; ++r) {
    bf16* op = Ob + (size_t)(b * Ssz + q0 + wave * 16 + quad * 4 + r) * Dm + h * 64 + m16;
#pragma unroll
    for (int nt = 0; nt < 4; ++nt) op[nt * 16] = f2bf(oacc[nt][r] * inv[r]);
  }
}

extern "C" void kernel_launch(void* const* d_in, const int* in_sizes, int n_in,
                              void* d_out, int out_size, void* d_ws, size_t ws_size,
                              hipStream_t stream) {
  char* ws = (char*)d_ws;
  int* flagp   = (int*)ws;                          // [0,1MB) control
  float* resid = (float*)(ws + (1ull << 20));       // 16MB fp32 residual
  bf16* xln    = (bf16*)(ws + (17ull << 20));       // 8MB LN output
  bf16* aout   = (bf16*)(ws + (25ull << 20));       // 8MB attn out
  bf16* big    = (bf16*)(ws + (33ull << 20));       // 32MB: qkv | qb | ffn1
  size_t off   = (65ull << 20);                     // canonical bf16 inputs

  detect_kernel<<<1, 64, 0, stream>>>((const unsigned*)d_in[3], flagp);

  // fused canonicalization of all inputs (skip tgt_mask, index 2)
  CanonArgs ca;
  bf16* c[23];
  for (int i = 0; i < 23; ++i) {
    if (i == 2) { c[i] = nullptr; ca.src[i] = d_in[i]; ca.dst[i] = nullptr; ca.n[i] = 0; continue; }
    c[i] = (bf16*)(ws + off);
    const int n = in_sizes[i];
    off += ((size_t)n * 2 + 255) & ~(size_t)255;
    ca.src[i] = d_in[i];
    ca.dst[i] = c[i];
    ca.n[i] = n;
  }
  canon_all<<<dim3(256, 23), 256, 0, stream>>>(ca, flagp);

  const bf16 *tgt = c[0], *memory = c[1], *rope_cos = c[3], *rope_sin = c[4];
  const bf16 *qkv_w = c[5], *qkv_b = c[6], *out_w = c[7], *out_b = c[8];
  const bf16 *ca_in_w = c[9], *ca_in_b = c[10], *ca_out_w = c[11], *ca_out_b = c[12];
  const bf16 *ffn_w1 = c[13], *ffn_b1 = c[14], *ffn_w2 = c[15], *ffn_b2 = c[16];
  const bf16 *ln1_g = c[17], *ln1_b = c[18], *ln2_g = c[19], *ln2_b = c[20];
  const bf16 *ln3_g = c[21], *ln3_b = c[22];

  bf16* qb = big;                               // 8MB  [33,41)
  bf16* kb = (bf16*)(ws + (41ull << 20));       // 2MB  [41,43)
  bf16* vb = (bf16*)(ws + (43ull << 20));       // 2MB  [43,45)
  bf16* outB = (bf16*)d_out;
  float* outF = (float*)d_out;

  const int ROWS = Bn * Ssz;   // 4096
  const float scale = 0.125f;  // 1/sqrt(64)

  to_f32_kernel<<<(ROWS * Dm) / (256 * 8), 256, 0, stream>>>(tgt, resid, ROWS * Dm);

  // ---- self attention ----
  ln_kernel<<<ROWS, 256, 0, stream>>>(resid, ln1_g, ln1_b, xln);
  gemm128<<<dim3(ROWS / 128, (3 * Dm) / 128), 256, 0, stream>>>(
      xln, qkv_w, qkv_b, big, nullptr, nullptr, nullptr, nullptr, ROWS, 3 * Dm, Dm, 0);
  rope_kernel<<<(ROWS * Hh * (HDd / 2)) / 256, 256, 0, stream>>>(big, rope_cos, rope_sin);
  attn_mfma<<<dim3(Ssz / 64, Hh, Bn), 256, 0, stream>>>(
      big, big + Dm, big + 2 * Dm, aout, 3 * Dm, 3 * Dm, Ssz, 1, scale);
  gemm128<<<dim3(ROWS / 128, Dm / 128), 256, 0, stream>>>(
      aout, out_w, out_b, nullptr, nullptr, resid, resid, nullptr, ROWS, Dm, Dm, 2);

  // ---- cross attention ----
  ln_kernel<<<ROWS, 256, 0, stream>>>(resid, ln2_g, ln2_b, xln);
  gemm128<<<dim3(ROWS / 128, Dm / 128), 256, 0, stream>>>(
      xln, ca_in_w, ca_in_b, qb, nullptr, nullptr, nullptr, nullptr, ROWS, Dm, Dm, 0);
  gemm_bt<<<dim3((Bn * MEMn) / 64, Dm / 64), 256, 0, stream>>>(
      memory, ca_in_w + (size_t)Dm * Dm, ca_in_b + Dm, kb, nullptr, nullptr, nullptr, nullptr,
      Bn * MEMn, Dm, Dm, 0);
  gemm_bt<<<dim3((Bn * MEMn) / 64, Dm / 64), 256, 0, stream>>>(
      memory, ca_in_w + (size_t)2 * Dm * Dm, ca_in_b + 2 * Dm, vb, nullptr, nullptr, nullptr, nullptr,
      Bn * MEMn, Dm, Dm, 0);
  attn_mfma<<<dim3(Ssz / 64, Hh, Bn), 256, 0, stream>>>(
      qb, kb, vb, aout, Dm, Dm, MEMn, 0, scale);
  gemm128<<<dim3(ROWS / 128, Dm / 128), 256, 0, stream>>>(
      aout, ca_out_w, ca_out_b, nullptr, nullptr, resid, resid, nullptr, ROWS, Dm, Dm, 2);

  // ---- FFN ----
  ln_kernel<<<ROWS, 256, 0, stream>>>(resid, ln3_g, ln3_b, xln);
  gemm128<<<dim3(ROWS / 128, DFFn / 128), 256, 0, stream>>>(
      xln, ffn_w1, ffn_b1, big, nullptr, nullptr, nullptr, nullptr, ROWS, DFFn, Dm, 1);
  gemm128<<<dim3(ROWS / 128, Dm / 128), 256, 0, stream>>>(
      big, ffn_w2, ffn_b2, outB, outF, resid, nullptr, flagp, ROWS, Dm, DFFn, 3);
}

// Round 5
// 635.166 us; speedup vs baseline: 1.9464x; 1.0399x over previous
//
#include <hip/hip_runtime.h>
#include <hip/hip_bf16.h>

// PhraseDecoderLayer: B=4,S=1024,D=1024,H=16,HD=64,DFF=4096,MEM=256.
// Round 5: gemm128 gets double-buffered LDS with prefetch-after-barrier
// (round 4's load-then-barrier exposed full load latency every K-step).
// canon_all also emits the fp32 residual for seg 0 (kills to_f32 pass).
// Attention / kv GEMMs / LN unchanged from passing rounds.

using bf16 = __hip_bfloat16;
typedef __bf16 bf16x8 __attribute__((ext_vector_type(8)));
typedef float f32x4 __attribute__((ext_vector_type(4)));
typedef __attribute__((address_space(3))) void lds_void;
typedef const __attribute__((address_space(1))) void glob_void;

static constexpr int Bn = 4, Ssz = 1024, Dm = 1024, Hh = 16, HDd = 64, DFFn = 4096, MEMn = 256;

__device__ inline float bf2f(bf16 x) { return __bfloat162float(x); }
__device__ inline bf16 f2bf(float x) { return __float2bfloat16(x); }

__device__ inline void load8(const bf16* p, float* o) {
  float4 raw = *reinterpret_cast<const float4*>(p);
  const unsigned short* u = reinterpret_cast<const unsigned short*>(&raw);
#pragma unroll
  for (int j = 0; j < 8; ++j) o[j] = __uint_as_float(((unsigned)u[j]) << 16);
}

// ---------------- dtype detect ----------------
__global__ void detect_kernel(const unsigned* __restrict__ cosw, int* __restrict__ flag) {
  if (threadIdx.x == 0) *flag = (cosw[0] == 0x3F800000u) ? 1 : 0;
}

// ---------------- fused canonicalize: all inputs -> bf16 (+f32 resid for seg0) ----
struct CanonArgs {
  const void* src[23];
  void* dst[23];
  int n[23];  // element count (0 = skip); all counts divisible by 4
};
__global__ __launch_bounds__(256) void canon_all(CanonArgs a, float* __restrict__ resid,
                                                 const int* __restrict__ flagp) {
  const int seg = blockIdx.y;
  const int n4 = a.n[seg] >> 2;
  if (n4 == 0) return;
  const int fl = *flagp;  // wave-uniform
  if (fl) {
    const float4* s = (const float4*)a.src[seg];
    bf16* d = (bf16*)a.dst[seg];
    for (int i = blockIdx.x * 256 + threadIdx.x; i < n4; i += gridDim.x * 256) {
      float4 v = s[i];
      bf16 t[4] = {f2bf(v.x), f2bf(v.y), f2bf(v.z), f2bf(v.w)};
      *reinterpret_cast<unsigned long long*>(d + i * 4) =
          *reinterpret_cast<unsigned long long*>(t);
      if (seg == 0) *reinterpret_cast<float4*>(resid + i * 4) = v;
    }
  } else {
    const unsigned long long* s = (const unsigned long long*)a.src[seg];
    unsigned long long* d = (unsigned long long*)a.dst[seg];
    for (int i = blockIdx.x * 256 + threadIdx.x; i < n4; i += gridDim.x * 256) {
      unsigned long long v = s[i];
      d[i] = v;
      if (seg == 0) {
        const unsigned short* u = reinterpret_cast<const unsigned short*>(&v);
        float4 f;
        f.x = __uint_as_float(((unsigned)u[0]) << 16);
        f.y = __uint_as_float(((unsigned)u[1]) << 16);
        f.z = __uint_as_float(((unsigned)u[2]) << 16);
        f.w = __uint_as_float(((unsigned)u[3]) << 16);
        *reinterpret_cast<float4*>(resid + i * 4) = f;
      }
    }
  }
}

// ---------------- LayerNorm (rows of 1024, fp32 in, bf16 out) ----------------
__global__ __launch_bounds__(256) void ln_kernel(const float* __restrict__ x,
                                                 const bf16* __restrict__ g,
                                                 const bf16* __restrict__ bb,
                                                 bf16* __restrict__ y) {
  const int row = blockIdx.x;
  const float* xr = x + (size_t)row * Dm;
  const int i0 = threadIdx.x * 4;
  float4 v = *reinterpret_cast<const float4*>(xr + i0);
  float s = v.x + v.y + v.z + v.w;
  float ss = v.x * v.x + v.y * v.y + v.z * v.z + v.w * v.w;
#pragma unroll
  for (int o = 32; o > 0; o >>= 1) {
    s += __shfl_down(s, o);
    ss += __shfl_down(ss, o);
  }
  __shared__ float shs[4], shss[4];
  const int wave = threadIdx.x >> 6, lane = threadIdx.x & 63;
  if (lane == 0) { shs[wave] = s; shss[wave] = ss; }
  __syncthreads();
  s = shs[0] + shs[1] + shs[2] + shs[3];
  ss = shss[0] + shss[1] + shss[2] + shss[3];
  const float mu = s * (1.0f / Dm);
  const float var = fmaxf(ss * (1.0f / Dm) - mu * mu, 0.0f);
  const float rs = rsqrtf(var + 1e-5f);
  bf16* yr = y + (size_t)row * Dm + i0;
  float vv[4] = {v.x, v.y, v.z, v.w};
#pragma unroll
  for (int j = 0; j < 4; ++j)
    yr[j] = f2bf((vv[j] - mu) * rs * bf2f(g[i0 + j]) + bf2f(bb[i0 + j]));
}

// ---------------- GEMM 64x64 (round-2 verified; used for M=1024 kv) --------
__global__ __launch_bounds__(256) void gemm_bt(
    const bf16* __restrict__ A, const bf16* __restrict__ W,
    const bf16* __restrict__ bias, bf16* __restrict__ outB, float* __restrict__ outF,
    const float* __restrict__ residIn, float* __restrict__ residOut,
    const int* __restrict__ flagp, int M, int N, int K, int epi) {
  __shared__ bf16 As[64][40];
  __shared__ bf16 Ws[64][40];
  const int tid = threadIdx.x;
  const int m0 = blockIdx.x * 64, n0 = blockIdx.y * 64;
  const int wave = tid >> 6, lane = tid & 63;
  const int wm = wave >> 1, wn = wave & 1;
  const int quad = lane >> 4, m16 = lane & 15;
  const int lr = tid >> 2, lc = (tid & 3) * 8;

  f32x4 acc[2][2] = {};

  const bf16* Ap = A + (size_t)(m0 + lr) * K + lc;
  const bf16* Wp = W + (size_t)(n0 + lr) * K + lc;
  for (int k0 = 0; k0 < K; k0 += 32) {
    float4 av = *reinterpret_cast<const float4*>(Ap + k0);
    float4 wv = *reinterpret_cast<const float4*>(Wp + k0);
    *reinterpret_cast<float4*>(&As[lr][lc]) = av;
    *reinterpret_cast<float4*>(&Ws[lr][lc]) = wv;
    __syncthreads();
    bf16x8 aF[2], bF[2];
#pragma unroll
    for (int t = 0; t < 2; ++t) {
      aF[t] = *reinterpret_cast<const bf16x8*>(&As[wm * 32 + t * 16 + m16][quad * 8]);
      bF[t] = *reinterpret_cast<const bf16x8*>(&Ws[wn * 32 + t * 16 + m16][quad * 8]);
    }
#pragma unroll
    for (int mt = 0; mt < 2; ++mt)
#pragma unroll
      for (int nt = 0; nt < 2; ++nt)
        acc[mt][nt] = __builtin_amdgcn_mfma_f32_16x16x32_bf16(aF[mt], bF[nt], acc[mt][nt], 0, 0, 0);
    __syncthreads();
  }
  const int fl = (epi == 3) ? *flagp : 0;
#pragma unroll
  for (int mt = 0; mt < 2; ++mt) {
#pragma unroll
    for (int nt = 0; nt < 2; ++nt) {
      const int col = n0 + wn * 32 + nt * 16 + m16;
      const float bv = bf2f(bias[col]);
#pragma unroll
      for (int r = 0; r < 4; ++r) {
        const int row = m0 + wm * 32 + mt * 16 + quad * 4 + r;
        const size_t idx = (size_t)row * N + col;
        float v = acc[mt][nt][r] + bv;
        if (epi == 0) {
          outB[idx] = f2bf(v);
        } else if (epi == 1) {
          outB[idx] = f2bf(0.5f * v * (1.0f + erff(v * 0.70710678118654752f)));
        } else if (epi == 2) {
          residOut[idx] = residIn[idx] + v;
        } else {
          const float rr = residIn[idx] + v;
          if (fl) outF[idx] = rr; else outB[idx] = f2bf(rr);
        }
      }
    }
  }
}

// ---------------- GEMM 128x128, double-buffered LDS, prefetch-after-barrier --
// BK=32. Staging: wave w, half r covers rows (r*4+w)*16..+15 of the tile;
// lane l -> row base+l/4, col (l&3)*8 (contiguous in lane order, as
// global_load_lds requires). Prefetch for step s+1 is issued at the TOP of
// step s (right after the barrier), so its latency overlaps ds_read+MFMA;
// the end-of-step barrier drain only pays the residue.
__global__ __launch_bounds__(256) void gemm128(
    const bf16* __restrict__ A, const bf16* __restrict__ W,
    const bf16* __restrict__ bias, bf16* __restrict__ outB, float* __restrict__ outF,
    const float* __restrict__ residIn, float* __restrict__ residOut,
    const int* __restrict__ flagp, int M, int N, int K, int epi) {
  __shared__ bf16 As[2][128][32];
  __shared__ bf16 Ws[2][128][32];
  const int tid = threadIdx.x;
  const int wave = tid >> 6, lane = tid & 63;
  const int wm = wave >> 1, wn = wave & 1;
  const int quad = lane >> 4, m16 = lane & 15;
  const int m0 = blockIdx.x * 128, n0 = blockIdx.y * 128;

  const int srow = wave * 16 + (lane >> 2);
  const int scol = (lane & 3) * 8;
  const bf16* Ag = A + (size_t)(m0 + srow) * K + scol;
  const bf16* Wg = W + (size_t)(n0 + srow) * K + scol;

  f32x4 acc[4][4] = {};

  // preload tile 0 into buffer 0
#pragma unroll
  for (int r = 0; r < 2; ++r) {
    __builtin_amdgcn_global_load_lds((glob_void*)(Ag + (size_t)(r * 64) * K),
                                     (lds_void*)&As[0][(r * 4 + wave) * 16][0], 16, 0, 0);
    __builtin_amdgcn_global_load_lds((glob_void*)(Wg + (size_t)(r * 64) * K),
                                     (lds_void*)&Ws[0][(r * 4 + wave) * 16][0], 16, 0, 0);
  }
  __syncthreads();

  const int nsteps = K >> 5;
  for (int s = 0; s < nsteps; ++s) {
    const int cur = s & 1, nxt = cur ^ 1;
    // prefetch tile s+1 into the other buffer (in flight during MFMA below)
    if (s + 1 < nsteps) {
      const int k1 = (s + 1) * 32;
#pragma unroll
      for (int r = 0; r < 2; ++r) {
        __builtin_amdgcn_global_load_lds((glob_void*)(Ag + (size_t)(r * 64) * K + k1),
                                         (lds_void*)&As[nxt][(r * 4 + wave) * 16][0], 16, 0, 0);
        __builtin_amdgcn_global_load_lds((glob_void*)(Wg + (size_t)(r * 64) * K + k1),
                                         (lds_void*)&Ws[nxt][(r * 4 + wave) * 16][0], 16, 0, 0);
      }
    }
    bf16x8 aF[4], bF[4];
#pragma unroll
    for (int t = 0; t < 4; ++t) {
      aF[t] = *reinterpret_cast<const bf16x8*>(&As[cur][wm * 64 + t * 16 + m16][quad * 8]);
      bF[t] = *reinterpret_cast<const bf16x8*>(&Ws[cur][wn * 64 + t * 16 + m16][quad * 8]);
    }
#pragma unroll
    for (int mt = 0; mt < 4; ++mt)
#pragma unroll
      for (int nt = 0; nt < 4; ++nt)
        acc[mt][nt] = __builtin_amdgcn_mfma_f32_16x16x32_bf16(aF[mt], bF[nt], acc[mt][nt], 0, 0, 0);
    __syncthreads();  // drains prefetch residue + guards buffer swap
  }
  const int fl = (epi == 3) ? *flagp : 0;
  // C/D layout: col = lane&15, row = quad*4 + reg
#pragma unroll
  for (int mt = 0; mt < 4; ++mt) {
#pragma unroll
    for (int nt = 0; nt < 4; ++nt) {
      const int col = n0 + wn * 64 + nt * 16 + m16;
      const float bv = bf2f(bias[col]);
#pragma unroll
      for (int r = 0; r < 4; ++r) {
        const int row = m0 + wm * 64 + mt * 16 + quad * 4 + r;
        const size_t idx = (size_t)row * N + col;
        float v = acc[mt][nt][r] + bv;
        if (epi == 0) {
          outB[idx] = f2bf(v);
        } else if (epi == 1) {
          outB[idx] = f2bf(0.5f * v * (1.0f + erff(v * 0.70710678118654752f)));
        } else if (epi == 2) {
          residOut[idx] = residIn[idx] + v;
        } else {
          const float rr = residIn[idx] + v;
          if (fl) outF[idx] = rr; else outB[idx] = f2bf(rr);
        }
      }
    }
  }
}

// ---------------- RoPE in-place on qkv buffer [4096, 3072] ----------------
__global__ __launch_bounds__(256) void rope_kernel(bf16* __restrict__ qkv,
                                                   const bf16* __restrict__ cosb,
                                                   const bf16* __restrict__ sinb) {
  const int idx = blockIdx.x * 256 + threadIdx.x;  // over 4096*16*32
  const int i = idx & 31;
  const int h = (idx >> 5) & 15;
  const int r = idx >> 9;
  const int s = r & (Ssz - 1);
  const float c = bf2f(cosb[s * 32 + i]);
  const float sn = bf2f(sinb[s * 32 + i]);
  bf16* base = qkv + (size_t)r * (3 * Dm) + h * 64 + 2 * i;
  float x0 = bf2f(base[0]), x1 = bf2f(base[1]);
  base[0] = f2bf(x0 * c - x1 * sn);
  base[1] = f2bf(x0 * sn + x1 * c);
  x0 = bf2f(base[Dm]); x1 = bf2f(base[Dm + 1]);
  base[Dm] = f2bf(x0 * c - x1 * sn);
  base[Dm + 1] = f2bf(x0 * sn + x1 * c);
}

// ---------------- MFMA flash attention (round-3 verified) ----------------
__global__ __launch_bounds__(256) void attn_mfma(
    const bf16* __restrict__ Qb, const bf16* __restrict__ Kb, const bf16* __restrict__ Vb,
    bf16* __restrict__ Ob, int qStride, int kvStride, int kvLen, int causal, float scale) {
  __shared__ bf16 Ks[64][72];
  __shared__ bf16 Vt[64][72];
  __shared__ bf16 Ps[64][72];
  const int tid = threadIdx.x;
  const int wave = tid >> 6, lane = tid & 63;
  const int quad = lane >> 4, m16 = lane & 15;
  const int b = blockIdx.z, h = blockIdx.y;
  const int q0 = blockIdx.x * 64;
  const int sr = tid >> 2, sc = (tid & 3) * 16;

  {
    const bf16* qp = Qb + (size_t)(b * Ssz + q0 + sr) * qStride + h * 64 + sc;
    float4 a = reinterpret_cast<const float4*>(qp)[0];
    float4 bb2 = reinterpret_cast<const float4*>(qp)[1];
    *reinterpret_cast<float4*>(&Ps[sr][sc]) = a;
    *reinterpret_cast<float4*>(&Ps[sr][sc + 8]) = bb2;
  }
  __syncthreads();
  bf16x8 qf[2];
  qf[0] = *reinterpret_cast<const bf16x8*>(&Ps[wave * 16 + m16][quad * 8]);
  qf[1] = *reinterpret_cast<const bf16x8*>(&Ps[wave * 16 + m16][32 + quad * 8]);

  f32x4 oacc[4] = {};
  float mrow[4], lrow[4];
#pragma unroll
  for (int r = 0; r < 4; ++r) { mrow[r] = -30000.0f; lrow[r] = 0.0f; }

  const int nk = causal ? (q0 + 64) : kvLen;
  for (int kt = 0; kt < nk; kt += 64) {
    {
      const bf16* kp = Kb + (size_t)(b * kvLen + kt + sr) * kvStride + h * 64 + sc;
      float4 k1 = reinterpret_cast<const float4*>(kp)[0];
      float4 k2 = reinterpret_cast<const float4*>(kp)[1];
      *reinterpret_cast<float4*>(&Ks[sr][sc]) = k1;
      *reinterpret_cast<float4*>(&Ks[sr][sc + 8]) = k2;
      const bf16* vp = Vb + (size_t)(b * kvLen + kt + sr) * kvStride + h * 64 + sc;
      float4 v1 = reinterpret_cast<const float4*>(vp)[0];
      float4 v2 = reinterpret_cast<const float4*>(vp)[1];
      const bf16* tv1 = reinterpret_cast<const bf16*>(&v1);
      const bf16* tv2 = reinterpret_cast<const bf16*>(&v2);
#pragma unroll
      for (int j = 0; j < 8; ++j) {
        Vt[sc + j][sr] = tv1[j];
        Vt[sc + 8 + j][sr] = tv2[j];
      }
    }
    __syncthreads();

    f32x4 sacc[4] = {};
#pragma unroll
    for (int nt = 0; nt < 4; ++nt) {
      bf16x8 kf0 = *reinterpret_cast<const bf16x8*>(&Ks[nt * 16 + m16][quad * 8]);
      bf16x8 kf1 = *reinterpret_cast<const bf16x8*>(&Ks[nt * 16 + m16][32 + quad * 8]);
      sacc[nt] = __builtin_amdgcn_mfma_f32_16x16x32_bf16(qf[0], kf0, sacc[nt], 0, 0, 0);
      sacc[nt] = __builtin_amdgcn_mfma_f32_16x16x32_bf16(qf[1], kf1, sacc[nt], 0, 0, 0);
    }
    const bool dmask = (causal != 0) && (kt == q0);
#pragma unroll
    for (int nt = 0; nt < 4; ++nt) {
#pragma unroll
      for (int r = 0; r < 4; ++r) {
        float s = sacc[nt][r] * scale;
        if (dmask && (nt * 16 + m16 > wave * 16 + quad * 4 + r)) s = -30000.0f;
        sacc[nt][r] = s;
      }
    }

#pragma unroll
    for (int r = 0; r < 4; ++r) {
      float mx = fmaxf(fmaxf(sacc[0][r], sacc[1][r]), fmaxf(sacc[2][r], sacc[3][r]));
#pragma unroll
      for (int off = 1; off < 16; off <<= 1) mx = fmaxf(mx, __shfl_xor(mx, off));
      const float mn = fmaxf(mrow[r], mx);
      const float corr = __expf(mrow[r] - mn);
      mrow[r] = mn;
      float psum = 0.0f;
#pragma unroll
      for (int nt = 0; nt < 4; ++nt) {
        const float p = __expf(sacc[nt][r] - mn);
        sacc[nt][r] = p;
        psum += p;
      }
#pragma unroll
      for (int off = 1; off < 16; off <<= 1) psum += __shfl_xor(psum, off);
      lrow[r] = lrow[r] * corr + psum;
#pragma unroll
      for (int nt = 0; nt < 4; ++nt) oacc[nt][r] *= corr;
#pragma unroll
      for (int nt = 0; nt < 4; ++nt)
        Ps[wave * 16 + quad * 4 + r][nt * 16 + m16] = f2bf(sacc[nt][r]);
    }
    bf16x8 pf0 = *reinterpret_cast<const bf16x8*>(&Ps[wave * 16 + m16][quad * 8]);
    bf16x8 pf1 = *reinterpret_cast<const bf16x8*>(&Ps[wave * 16 + m16][32 + quad * 8]);
#pragma unroll
    for (int nt = 0; nt < 4; ++nt) {
      bf16x8 vf0 = *reinterpret_cast<const bf16x8*>(&Vt[nt * 16 + m16][quad * 8]);
      bf16x8 vf1 = *reinterpret_cast<const bf16x8*>(&Vt[nt * 16 + m16][32 + quad * 8]);
      oacc[nt] = __builtin_amdgcn_mfma_f32_16x16x32_bf16(pf0, vf0, oacc[nt], 0, 0, 0);
      oacc[nt] = __builtin_amdgcn_mfma_f32_16x16x32_bf16(pf1, vf1, oacc[nt], 0, 0, 0);
    }
    __syncthreads();
  }

  float inv[4];
#pragma unroll
  for (int r = 0; r < 4; ++r) inv[r] = 1.0f / lrow[r];
#pragma unroll
  for (int r = 0; r < 4; ++r) {
    bf16* op = Ob + (size_t)(b * Ssz + q0 + wave * 16 + quad * 4 + r) * Dm + h * 64 + m16;
#pragma unroll
    for (int nt = 0; nt < 4; ++nt) op[nt * 16] = f2bf(oacc[nt][r] * inv[r]);
  }
}

extern "C" void kernel_launch(void* const* d_in, const int* in_sizes, int n_in,
                              void* d_out, int out_size, void* d_ws, size_t ws_size,
                              hipStream_t stream) {
  char* ws = (char*)d_ws;
  int* flagp   = (int*)ws;                          // [0,1MB) control
  float* resid = (float*)(ws + (1ull << 20));       // 16MB fp32 residual
  bf16* xln    = (bf16*)(ws + (17ull << 20));       // 8MB LN output
  bf16* aout   = (bf16*)(ws + (25ull << 20));       // 8MB attn out
  bf16* big    = (bf16*)(ws + (33ull << 20));       // 32MB: qkv | qb | ffn1
  size_t off   = (65ull << 20);                     // canonical bf16 inputs

  detect_kernel<<<1, 64, 0, stream>>>((const unsigned*)d_in[3], flagp);

  CanonArgs ca;
  bf16* c[23];
  for (int i = 0; i < 23; ++i) {
    if (i == 2) { c[i] = nullptr; ca.src[i] = d_in[i]; ca.dst[i] = nullptr; ca.n[i] = 0; continue; }
    c[i] = (bf16*)(ws + off);
    const int n = in_sizes[i];
    off += ((size_t)n * 2 + 255) & ~(size_t)255;
    ca.src[i] = d_in[i];
    ca.dst[i] = c[i];
    ca.n[i] = n;
  }
  canon_all<<<dim3(256, 23), 256, 0, stream>>>(ca, resid, flagp);

  const bf16 *memory = c[1], *rope_cos = c[3], *rope_sin = c[4];
  const bf16 *qkv_w = c[5], *qkv_b = c[6], *out_w = c[7], *out_b = c[8];
  const bf16 *ca_in_w = c[9], *ca_in_b = c[10], *ca_out_w = c[11], *ca_out_b = c[12];
  const bf16 *ffn_w1 = c[13], *ffn_b1 = c[14], *ffn_w2 = c[15], *ffn_b2 = c[16];
  const bf16 *ln1_g = c[17], *ln1_b = c[18], *ln2_g = c[19], *ln2_b = c[20];
  const bf16 *ln3_g = c[21], *ln3_b = c[22];

  bf16* qb = big;
  bf16* kb = (bf16*)(ws + (41ull << 20));
  bf16* vb = (bf16*)(ws + (43ull << 20));
  bf16* outB = (bf16*)d_out;
  float* outF = (float*)d_out;

  const int ROWS = Bn * Ssz;   // 4096
  const float scale = 0.125f;  // 1/sqrt(64)

  // ---- self attention ----
  ln_kernel<<<ROWS, 256, 0, stream>>>(resid, ln1_g, ln1_b, xln);
  gemm128<<<dim3(ROWS / 128, (3 * Dm) / 128), 256, 0, stream>>>(
      xln, qkv_w, qkv_b, big, nullptr, nullptr, nullptr, nullptr, ROWS, 3 * Dm, Dm, 0);
  rope_kernel<<<(ROWS * Hh * (HDd / 2)) / 256, 256, 0, stream>>>(big, rope_cos, rope_sin);
  attn_mfma<<<dim3(Ssz / 64, Hh, Bn), 256, 0, stream>>>(
      big, big + Dm, big + 2 * Dm, aout, 3 * Dm, 3 * Dm, Ssz, 1, scale);
  gemm128<<<dim3(ROWS / 128, Dm / 128), 256, 0, stream>>>(
      aout, out_w, out_b, nullptr, nullptr, resid, resid, nullptr, ROWS, Dm, Dm, 2);

  // ---- cross attention ----
  ln_kernel<<<ROWS, 256, 0, stream>>>(resid, ln2_g, ln2_b, xln);
  gemm128<<<dim3(ROWS / 128, Dm / 128), 256, 0, stream>>>(
      xln, ca_in_w, ca_in_b, qb, nullptr, nullptr, nullptr, nullptr, ROWS, Dm, Dm, 0);
  gemm_bt<<<dim3((Bn * MEMn) / 64, Dm / 64), 256, 0, stream>>>(
      memory, ca_in_w + (size_t)Dm * Dm, ca_in_b + Dm, kb, nullptr, nullptr, nullptr, nullptr,
      Bn * MEMn, Dm, Dm, 0);
  gemm_bt<<<dim3((Bn * MEMn) / 64, Dm / 64), 256, 0, stream>>>(
      memory, ca_in_w + (size_t)2 * Dm * Dm, ca_in_b + 2 * Dm, vb, nullptr, nullptr, nullptr, nullptr,
      Bn * MEMn, Dm, Dm, 0);
  attn_mfma<<<dim3(Ssz / 64, Hh, Bn), 256, 0, stream>>>(
      qb, kb, vb, aout, Dm, Dm, MEMn, 0, scale);
  gemm128<<<dim3(ROWS / 128, Dm / 128), 256, 0, stream>>>(
      aout, ca_out_w, ca_out_b, nullptr, nullptr, resid, resid, nullptr, ROWS, Dm, Dm, 2);

  // ---- FFN ----
  ln_kernel<<<ROWS, 256, 0, stream>>>(resid, ln3_g, ln3_b, xln);
  gemm128<<<dim3(ROWS / 128, DFFn / 128), 256, 0, stream>>>(
      xln, ffn_w1, ffn_b1, big, nullptr, nullptr, nullptr, nullptr, ROWS, DFFn, Dm, 1);
  gemm128<<<dim3(ROWS / 128, Dm / 128), 256, 0, stream>>>(
      big, ffn_w2, ffn_b2, outB, outF, resid, nullptr, flagp, ROWS, Dm, DFFn, 3);
}

// Round 6
// 607.835 us; speedup vs baseline: 2.0339x; 1.0450x over previous
//
#include <hip/hip_runtime.h>
#include <hip/hip_bf16.h>

// PhraseDecoderLayer: B=4,S=1024,D=1024,H=16,HD=64,DFF=4096,MEM=256.
// Round 6: gemm128 rewritten as global->VGPR->LDS register pipeline with
// PADDED LDS tiles ([128][40], conflict-free b128 reads). Prefetch of tile
// s+1 into registers is issued before the MFMA block of tile s; the
// compiler's vmcnt wait lands at the ds_write of the NEXT step, so global
// latency overlaps a full MFMA block. (global_load_lds removed: it forced
// unpadded LDS -> 4-way bank conflicts, and its prefetch window was ~125cyc
// vs ~200-900cyc latency at K=1024.)
// Attention / kv GEMMs / LN / canon unchanged from passing rounds.

using bf16 = __hip_bfloat16;
typedef __bf16 bf16x8 __attribute__((ext_vector_type(8)));
typedef float f32x4 __attribute__((ext_vector_type(4)));

static constexpr int Bn = 4, Ssz = 1024, Dm = 1024, Hh = 16, HDd = 64, DFFn = 4096, MEMn = 256;

__device__ inline float bf2f(bf16 x) { return __bfloat162float(x); }
__device__ inline bf16 f2bf(float x) { return __float2bfloat16(x); }

// ---------------- dtype detect ----------------
__global__ void detect_kernel(const unsigned* __restrict__ cosw, int* __restrict__ flag) {
  if (threadIdx.x == 0) *flag = (cosw[0] == 0x3F800000u) ? 1 : 0;
}

// ---------------- fused canonicalize: all inputs -> bf16 (+f32 resid for seg0) ----
struct CanonArgs {
  const void* src[23];
  void* dst[23];
  int n[23];  // element count (0 = skip); all counts divisible by 4
};
__global__ __launch_bounds__(256) void canon_all(CanonArgs a, float* __restrict__ resid,
                                                 const int* __restrict__ flagp) {
  const int seg = blockIdx.y;
  const int n4 = a.n[seg] >> 2;
  if (n4 == 0) return;
  const int fl = *flagp;  // wave-uniform
  if (fl) {
    const float4* s = (const float4*)a.src[seg];
    bf16* d = (bf16*)a.dst[seg];
    for (int i = blockIdx.x * 256 + threadIdx.x; i < n4; i += gridDim.x * 256) {
      float4 v = s[i];
      bf16 t[4] = {f2bf(v.x), f2bf(v.y), f2bf(v.z), f2bf(v.w)};
      *reinterpret_cast<unsigned long long*>(d + i * 4) =
          *reinterpret_cast<unsigned long long*>(t);
      if (seg == 0) *reinterpret_cast<float4*>(resid + i * 4) = v;
    }
  } else {
    const unsigned long long* s = (const unsigned long long*)a.src[seg];
    unsigned long long* d = (unsigned long long*)a.dst[seg];
    for (int i = blockIdx.x * 256 + threadIdx.x; i < n4; i += gridDim.x * 256) {
      unsigned long long v = s[i];
      d[i] = v;
      if (seg == 0) {
        const unsigned short* u = reinterpret_cast<const unsigned short*>(&v);
        float4 f;
        f.x = __uint_as_float(((unsigned)u[0]) << 16);
        f.y = __uint_as_float(((unsigned)u[1]) << 16);
        f.z = __uint_as_float(((unsigned)u[2]) << 16);
        f.w = __uint_as_float(((unsigned)u[3]) << 16);
        *reinterpret_cast<float4*>(resid + i * 4) = f;
      }
    }
  }
}

// ---------------- LayerNorm (rows of 1024, fp32 in, bf16 out) ----------------
__global__ __launch_bounds__(256) void ln_kernel(const float* __restrict__ x,
                                                 const bf16* __restrict__ g,
                                                 const bf16* __restrict__ bb,
                                                 bf16* __restrict__ y) {
  const int row = blockIdx.x;
  const float* xr = x + (size_t)row * Dm;
  const int i0 = threadIdx.x * 4;
  float4 v = *reinterpret_cast<const float4*>(xr + i0);
  float s = v.x + v.y + v.z + v.w;
  float ss = v.x * v.x + v.y * v.y + v.z * v.z + v.w * v.w;
#pragma unroll
  for (int o = 32; o > 0; o >>= 1) {
    s += __shfl_down(s, o);
    ss += __shfl_down(ss, o);
  }
  __shared__ float shs[4], shss[4];
  const int wave = threadIdx.x >> 6, lane = threadIdx.x & 63;
  if (lane == 0) { shs[wave] = s; shss[wave] = ss; }
  __syncthreads();
  s = shs[0] + shs[1] + shs[2] + shs[3];
  ss = shss[0] + shss[1] + shss[2] + shss[3];
  const float mu = s * (1.0f / Dm);
  const float var = fmaxf(ss * (1.0f / Dm) - mu * mu, 0.0f);
  const float rs = rsqrtf(var + 1e-5f);
  bf16* yr = y + (size_t)row * Dm + i0;
  float vv[4] = {v.x, v.y, v.z, v.w};
#pragma unroll
  for (int j = 0; j < 4; ++j)
    yr[j] = f2bf((vv[j] - mu) * rs * bf2f(g[i0 + j]) + bf2f(bb[i0 + j]));
}

// ---------------- GEMM 64x64 (round-2 verified; used for M=1024 kv) --------
__global__ __launch_bounds__(256) void gemm_bt(
    const bf16* __restrict__ A, const bf16* __restrict__ W,
    const bf16* __restrict__ bias, bf16* __restrict__ outB, float* __restrict__ outF,
    const float* __restrict__ residIn, float* __restrict__ residOut,
    const int* __restrict__ flagp, int M, int N, int K, int epi) {
  __shared__ bf16 As[64][40];
  __shared__ bf16 Ws[64][40];
  const int tid = threadIdx.x;
  const int m0 = blockIdx.x * 64, n0 = blockIdx.y * 64;
  const int wave = tid >> 6, lane = tid & 63;
  const int wm = wave >> 1, wn = wave & 1;
  const int quad = lane >> 4, m16 = lane & 15;
  const int lr = tid >> 2, lc = (tid & 3) * 8;

  f32x4 acc[2][2] = {};

  const bf16* Ap = A + (size_t)(m0 + lr) * K + lc;
  const bf16* Wp = W + (size_t)(n0 + lr) * K + lc;
  for (int k0 = 0; k0 < K; k0 += 32) {
    float4 av = *reinterpret_cast<const float4*>(Ap + k0);
    float4 wv = *reinterpret_cast<const float4*>(Wp + k0);
    *reinterpret_cast<float4*>(&As[lr][lc]) = av;
    *reinterpret_cast<float4*>(&Ws[lr][lc]) = wv;
    __syncthreads();
    bf16x8 aF[2], bF[2];
#pragma unroll
    for (int t = 0; t < 2; ++t) {
      aF[t] = *reinterpret_cast<const bf16x8*>(&As[wm * 32 + t * 16 + m16][quad * 8]);
      bF[t] = *reinterpret_cast<const bf16x8*>(&Ws[wn * 32 + t * 16 + m16][quad * 8]);
    }
#pragma unroll
    for (int mt = 0; mt < 2; ++mt)
#pragma unroll
      for (int nt = 0; nt < 2; ++nt)
        acc[mt][nt] = __builtin_amdgcn_mfma_f32_16x16x32_bf16(aF[mt], bF[nt], acc[mt][nt], 0, 0, 0);
    __syncthreads();
  }
  const int fl = (epi == 3) ? *flagp : 0;
#pragma unroll
  for (int mt = 0; mt < 2; ++mt) {
#pragma unroll
    for (int nt = 0; nt < 2; ++nt) {
      const int col = n0 + wn * 32 + nt * 16 + m16;
      const float bv = bf2f(bias[col]);
#pragma unroll
      for (int r = 0; r < 4; ++r) {
        const int row = m0 + wm * 32 + mt * 16 + quad * 4 + r;
        const size_t idx = (size_t)row * N + col;
        float v = acc[mt][nt][r] + bv;
        if (epi == 0) {
          outB[idx] = f2bf(v);
        } else if (epi == 1) {
          outB[idx] = f2bf(0.5f * v * (1.0f + erff(v * 0.70710678118654752f)));
        } else if (epi == 2) {
          residOut[idx] = residIn[idx] + v;
        } else {
          const float rr = residIn[idx] + v;
          if (fl) outF[idx] = rr; else outB[idx] = f2bf(rr);
        }
      }
    }
  }
}

// ---------------- GEMM 128x128, register-staged pipeline, padded LDS --------
// Per K-step (BK=32): commit regs(tile s)->LDS, barrier, issue global loads
// for tile s+1 into regs (latency spans MFMA block), ds_read frags + 16 MFMA,
// barrier. Padded [128][40] rows (80B stride) -> conflict-free ds_read_b128.
__global__ __launch_bounds__(256) void gemm128(
    const bf16* __restrict__ A, const bf16* __restrict__ W,
    const bf16* __restrict__ bias, bf16* __restrict__ outB, float* __restrict__ outF,
    const float* __restrict__ residIn, float* __restrict__ residOut,
    const int* __restrict__ flagp, int M, int N, int K, int epi) {
  __shared__ bf16 As[128][40];
  __shared__ bf16 Ws[128][40];
  const int tid = threadIdx.x;
  const int wave = tid >> 6, lane = tid & 63;
  const int wm = wave >> 1, wn = wave & 1;
  const int quad = lane >> 4, m16 = lane & 15;
  const int m0 = blockIdx.x * 128, n0 = blockIdx.y * 128;

  const int lr = tid >> 2;         // 0..63
  const int lc = (tid & 3) * 8;    // 0,8,16,24
  const bf16* Ap = A + (size_t)(m0 + lr) * K + lc;
  const bf16* Wp = W + (size_t)(n0 + lr) * K + lc;
  const size_t rowOff = (size_t)64 * K;

  f32x4 acc[4][4] = {};

  // prologue: tile 0 into registers
  float4 ar0 = *reinterpret_cast<const float4*>(Ap);
  float4 ar1 = *reinterpret_cast<const float4*>(Ap + rowOff);
  float4 wr0 = *reinterpret_cast<const float4*>(Wp);
  float4 wr1 = *reinterpret_cast<const float4*>(Wp + rowOff);

  const int nsteps = K >> 5;
  for (int s = 0; s < nsteps; ++s) {
    // commit tile s to LDS (compiler waits vmcnt here — loads had the whole
    // previous MFMA block to complete)
    *reinterpret_cast<float4*>(&As[lr][lc]) = ar0;
    *reinterpret_cast<float4*>(&As[64 + lr][lc]) = ar1;
    *reinterpret_cast<float4*>(&Ws[lr][lc]) = wr0;
    *reinterpret_cast<float4*>(&Ws[64 + lr][lc]) = wr1;
    __syncthreads();
    // prefetch tile s+1 into registers (no use until next iteration's commit)
    if (s + 1 < nsteps) {
      const int k1 = (s + 1) * 32;
      ar0 = *reinterpret_cast<const float4*>(Ap + k1);
      ar1 = *reinterpret_cast<const float4*>(Ap + rowOff + k1);
      wr0 = *reinterpret_cast<const float4*>(Wp + k1);
      wr1 = *reinterpret_cast<const float4*>(Wp + rowOff + k1);
    }
    bf16x8 aF[4], bF[4];
#pragma unroll
    for (int t = 0; t < 4; ++t) {
      aF[t] = *reinterpret_cast<const bf16x8*>(&As[wm * 64 + t * 16 + m16][quad * 8]);
      bF[t] = *reinterpret_cast<const bf16x8*>(&Ws[wn * 64 + t * 16 + m16][quad * 8]);
    }
#pragma unroll
    for (int mt = 0; mt < 4; ++mt)
#pragma unroll
      for (int nt = 0; nt < 4; ++nt)
        acc[mt][nt] = __builtin_amdgcn_mfma_f32_16x16x32_bf16(aF[mt], bF[nt], acc[mt][nt], 0, 0, 0);
    __syncthreads();  // all waves done reading before next commit
  }
  const int fl = (epi == 3) ? *flagp : 0;
  // C/D layout: col = lane&15, row = quad*4 + reg
#pragma unroll
  for (int mt = 0; mt < 4; ++mt) {
#pragma unroll
    for (int nt = 0; nt < 4; ++nt) {
      const int col = n0 + wn * 64 + nt * 16 + m16;
      const float bv = bf2f(bias[col]);
#pragma unroll
      for (int r = 0; r < 4; ++r) {
        const int row = m0 + wm * 64 + mt * 16 + quad * 4 + r;
        const size_t idx = (size_t)row * N + col;
        float v = acc[mt][nt][r] + bv;
        if (epi == 0) {
          outB[idx] = f2bf(v);
        } else if (epi == 1) {
          outB[idx] = f2bf(0.5f * v * (1.0f + erff(v * 0.70710678118654752f)));
        } else if (epi == 2) {
          residOut[idx] = residIn[idx] + v;
        } else {
          const float rr = residIn[idx] + v;
          if (fl) outF[idx] = rr; else outB[idx] = f2bf(rr);
        }
      }
    }
  }
}

// ---------------- RoPE in-place on qkv buffer [4096, 3072] ----------------
__global__ __launch_bounds__(256) void rope_kernel(bf16* __restrict__ qkv,
                                                   const bf16* __restrict__ cosb,
                                                   const bf16* __restrict__ sinb) {
  const int idx = blockIdx.x * 256 + threadIdx.x;  // over 4096*16*32
  const int i = idx & 31;
  const int h = (idx >> 5) & 15;
  const int r = idx >> 9;
  const int s = r & (Ssz - 1);
  const float c = bf2f(cosb[s * 32 + i]);
  const float sn = bf2f(sinb[s * 32 + i]);
  bf16* base = qkv + (size_t)r * (3 * Dm) + h * 64 + 2 * i;
  float x0 = bf2f(base[0]), x1 = bf2f(base[1]);
  base[0] = f2bf(x0 * c - x1 * sn);
  base[1] = f2bf(x0 * sn + x1 * c);
  x0 = bf2f(base[Dm]); x1 = bf2f(base[Dm + 1]);
  base[Dm] = f2bf(x0 * c - x1 * sn);
  base[Dm + 1] = f2bf(x0 * sn + x1 * c);
}

// ---------------- MFMA flash attention (round-3 verified) ----------------
__global__ __launch_bounds__(256) void attn_mfma(
    const bf16* __restrict__ Qb, const bf16* __restrict__ Kb, const bf16* __restrict__ Vb,
    bf16* __restrict__ Ob, int qStride, int kvStride, int kvLen, int causal, float scale) {
  __shared__ bf16 Ks[64][72];
  __shared__ bf16 Vt[64][72];
  __shared__ bf16 Ps[64][72];
  const int tid = threadIdx.x;
  const int wave = tid >> 6, lane = tid & 63;
  const int quad = lane >> 4, m16 = lane & 15;
  const int b = blockIdx.z, h = blockIdx.y;
  const int q0 = blockIdx.x * 64;
  const int sr = tid >> 2, sc = (tid & 3) * 16;

  {
    const bf16* qp = Qb + (size_t)(b * Ssz + q0 + sr) * qStride + h * 64 + sc;
    float4 a = reinterpret_cast<const float4*>(qp)[0];
    float4 bb2 = reinterpret_cast<const float4*>(qp)[1];
    *reinterpret_cast<float4*>(&Ps[sr][sc]) = a;
    *reinterpret_cast<float4*>(&Ps[sr][sc + 8]) = bb2;
  }
  __syncthreads();
  bf16x8 qf[2];
  qf[0] = *reinterpret_cast<const bf16x8*>(&Ps[wave * 16 + m16][quad * 8]);
  qf[1] = *reinterpret_cast<const bf16x8*>(&Ps[wave * 16 + m16][32 + quad * 8]);

  f32x4 oacc[4] = {};
  float mrow[4], lrow[4];
#pragma unroll
  for (int r = 0; r < 4; ++r) { mrow[r] = -30000.0f; lrow[r] = 0.0f; }

  const int nk = causal ? (q0 + 64) : kvLen;
  for (int kt = 0; kt < nk; kt += 64) {
    {
      const bf16* kp = Kb + (size_t)(b * kvLen + kt + sr) * kvStride + h * 64 + sc;
      float4 k1 = reinterpret_cast<const float4*>(kp)[0];
      float4 k2 = reinterpret_cast<const float4*>(kp)[1];
      *reinterpret_cast<float4*>(&Ks[sr][sc]) = k1;
      *reinterpret_cast<float4*>(&Ks[sr][sc + 8]) = k2;
      const bf16* vp = Vb + (size_t)(b * kvLen + kt + sr) * kvStride + h * 64 + sc;
      float4 v1 = reinterpret_cast<const float4*>(vp)[0];
      float4 v2 = reinterpret_cast<const float4*>(vp)[1];
      const bf16* tv1 = reinterpret_cast<const bf16*>(&v1);
      const bf16* tv2 = reinterpret_cast<const bf16*>(&v2);
#pragma unroll
      for (int j = 0; j < 8; ++j) {
        Vt[sc + j][sr] = tv1[j];
        Vt[sc + 8 + j][sr] = tv2[j];
      }
    }
    __syncthreads();

    f32x4 sacc[4] = {};
#pragma unroll
    for (int nt = 0; nt < 4; ++nt) {
      bf16x8 kf0 = *reinterpret_cast<const bf16x8*>(&Ks[nt * 16 + m16][quad * 8]);
      bf16x8 kf1 = *reinterpret_cast<const bf16x8*>(&Ks[nt * 16 + m16][32 + quad * 8]);
      sacc[nt] = __builtin_amdgcn_mfma_f32_16x16x32_bf16(qf[0], kf0, sacc[nt], 0, 0, 0);
      sacc[nt] = __builtin_amdgcn_mfma_f32_16x16x32_bf16(qf[1], kf1, sacc[nt], 0, 0, 0);
    }
    const bool dmask = (causal != 0) && (kt == q0);
#pragma unroll
    for (int nt = 0; nt < 4; ++nt) {
#pragma unroll
      for (int r = 0; r < 4; ++r) {
        float s = sacc[nt][r] * scale;
        if (dmask && (nt * 16 + m16 > wave * 16 + quad * 4 + r)) s = -30000.0f;
        sacc[nt][r] = s;
      }
    }

#pragma unroll
    for (int r = 0; r < 4; ++r) {
      float mx = fmaxf(fmaxf(sacc[0][r], sacc[1][r]), fmaxf(sacc[2][r], sacc[3][r]));
#pragma unroll
      for (int off = 1; off < 16; off <<= 1) mx = fmaxf(mx, __shfl_xor(mx, off));
      const float mn = fmaxf(mrow[r], mx);
      const float corr = __expf(mrow[r] - mn);
      mrow[r] = mn;
      float psum = 0.0f;
#pragma unroll
      for (int nt = 0; nt < 4; ++nt) {
        const float p = __expf(sacc[nt][r] - mn);
        sacc[nt][r] = p;
        psum += p;
      }
#pragma unroll
      for (int off = 1; off < 16; off <<= 1) psum += __shfl_xor(psum, off);
      lrow[r] = lrow[r] * corr + psum;
#pragma unroll
      for (int nt = 0; nt < 4; ++nt) oacc[nt][r] *= corr;
#pragma unroll
      for (int nt = 0; nt < 4; ++nt)
        Ps[wave * 16 + quad * 4 + r][nt * 16 + m16] = f2bf(sacc[nt][r]);
    }
    bf16x8 pf0 = *reinterpret_cast<const bf16x8*>(&Ps[wave * 16 + m16][quad * 8]);
    bf16x8 pf1 = *reinterpret_cast<const bf16x8*>(&Ps[wave * 16 + m16][32 + quad * 8]);
#pragma unroll
    for (int nt = 0; nt < 4; ++nt) {
      bf16x8 vf0 = *reinterpret_cast<const bf16x8*>(&Vt[nt * 16 + m16][quad * 8]);
      bf16x8 vf1 = *reinterpret_cast<const bf16x8*>(&Vt[nt * 16 + m16][32 + quad * 8]);
      oacc[nt] = __builtin_amdgcn_mfma_f32_16x16x32_bf16(pf0, vf0, oacc[nt], 0, 0, 0);
      oacc[nt] = __builtin_amdgcn_mfma_f32_16x16x32_bf16(pf1, vf1, oacc[nt], 0, 0, 0);
    }
    __syncthreads();
  }

  float inv[4];
#pragma unroll
  for (int r = 0; r < 4; ++r) inv[r] = 1.0f / lrow[r];
#pragma unroll
  for (int r = 0; r < 4; ++r) {
    bf16* op = Ob + (size_t)(b * Ssz + q0 + wave * 16 + quad * 4 + r) * Dm + h * 64 + m16;
#pragma unroll
    for (int nt = 0; nt < 4; ++nt) op[nt * 16] = f2bf(oacc[nt][r] * inv[r]);
  }
}

extern "C" void kernel_launch(void* const* d_in, const int* in_sizes, int n_in,
                              void* d_out, int out_size, void* d_ws, size_t ws_size,
                              hipStream_t stream) {
  char* ws = (char*)d_ws;
  int* flagp   = (int*)ws;                          // [0,1MB) control
  float* resid = (float*)(ws + (1ull << 20));       // 16MB fp32 residual
  bf16* xln    = (bf16*)(ws + (17ull << 20));       // 8MB LN output
  bf16* aout   = (bf16*)(ws + (25ull << 20));       // 8MB attn out
  bf16* big    = (bf16*)(ws + (33ull << 20));       // 32MB: qkv | qb | ffn1
  size_t off   = (65ull << 20);                     // canonical bf16 inputs

  detect_kernel<<<1, 64, 0, stream>>>((const unsigned*)d_in[3], flagp);

  CanonArgs ca;
  bf16* c[23];
  for (int i = 0; i < 23; ++i) {
    if (i == 2) { c[i] = nullptr; ca.src[i] = d_in[i]; ca.dst[i] = nullptr; ca.n[i] = 0; continue; }
    c[i] = (bf16*)(ws + off);
    const int n = in_sizes[i];
    off += ((size_t)n * 2 + 255) & ~(size_t)255;
    ca.src[i] = d_in[i];
    ca.dst[i] = c[i];
    ca.n[i] = n;
  }
  canon_all<<<dim3(256, 23), 256, 0, stream>>>(ca, resid, flagp);

  const bf16 *memory = c[1], *rope_cos = c[3], *rope_sin = c[4];
  const bf16 *qkv_w = c[5], *qkv_b = c[6], *out_w = c[7], *out_b = c[8];
  const bf16 *ca_in_w = c[9], *ca_in_b = c[10], *ca_out_w = c[11], *ca_out_b = c[12];
  const bf16 *ffn_w1 = c[13], *ffn_b1 = c[14], *ffn_w2 = c[15], *ffn_b2 = c[16];
  const bf16 *ln1_g = c[17], *ln1_b = c[18], *ln2_g = c[19], *ln2_b = c[20];
  const bf16 *ln3_g = c[21], *ln3_b = c[22];

  bf16* qb = big;
  bf16* kb = (bf16*)(ws + (41ull << 20));
  bf16* vb = (bf16*)(ws + (43ull << 20));
  bf16* outB = (bf16*)d_out;
  float* outF = (float*)d_out;

  const int ROWS = Bn * Ssz;   // 4096
  const float scale = 0.125f;  // 1/sqrt(64)

  // ---- self attention ----
  ln_kernel<<<ROWS, 256, 0, stream>>>(resid, ln1_g, ln1_b, xln);
  gemm128<<<dim3(ROWS / 128, (3 * Dm) / 128), 256, 0, stream>>>(
      xln, qkv_w, qkv_b, big, nullptr, nullptr, nullptr, nullptr, ROWS, 3 * Dm, Dm, 0);
  rope_kernel<<<(ROWS * Hh * (HDd / 2)) / 256, 256, 0, stream>>>(big, rope_cos, rope_sin);
  attn_mfma<<<dim3(Ssz / 64, Hh, Bn), 256, 0, stream>>>(
      big, big + Dm, big + 2 * Dm, aout, 3 * Dm, 3 * Dm, Ssz, 1, scale);
  gemm128<<<dim3(ROWS / 128, Dm / 128), 256, 0, stream>>>(
      aout, out_w, out_b, nullptr, nullptr, resid, resid, nullptr, ROWS, Dm, Dm, 2);

  // ---- cross attention ----
  ln_kernel<<<ROWS, 256, 0, stream>>>(resid, ln2_g, ln2_b, xln);
  gemm128<<<dim3(ROWS / 128, Dm / 128), 256, 0, stream>>>(
      xln, ca_in_w, ca_in_b, qb, nullptr, nullptr, nullptr, nullptr, ROWS, Dm, Dm, 0);
  gemm_bt<<<dim3((Bn * MEMn) / 64, Dm / 64), 256, 0, stream>>>(
      memory, ca_in_w + (size_t)Dm * Dm, ca_in_b + Dm, kb, nullptr, nullptr, nullptr, nullptr,
      Bn * MEMn, Dm, Dm, 0);
  gemm_bt<<<dim3((Bn * MEMn) / 64, Dm / 64), 256, 0, stream>>>(
      memory, ca_in_w + (size_t)2 * Dm * Dm, ca_in_b + 2 * Dm, vb, nullptr, nullptr, nullptr, nullptr,
      Bn * MEMn, Dm, Dm, 0);
  attn_mfma<<<dim3(Ssz / 64, Hh, Bn), 256, 0, stream>>>(
      qb, kb, vb, aout, Dm, Dm, MEMn, 0, scale);
  gemm128<<<dim3(ROWS / 128, Dm / 128), 256, 0, stream>>>(
      aout, ca_out_w, ca_out_b, nullptr, nullptr, resid, resid, nullptr, ROWS, Dm, Dm, 2);

  // ---- FFN ----
  ln_kernel<<<ROWS, 256, 0, stream>>>(resid, ln3_g, ln3_b, xln);
  gemm128<<<dim3(ROWS / 128, DFFn / 128), 256, 0, stream>>>(
      xln, ffn_w1, ffn_b1, big, nullptr, nullptr, nullptr, nullptr, ROWS, DFFn, Dm, 1);
  gemm128<<<dim3(ROWS / 128, Dm / 128), 256, 0, stream>>>(
      big, ffn_w2, ffn_b2, outB, outF, resid, nullptr, flagp, ROWS, Dm, DFFn, 3);
}

// Round 7
// 584.520 us; speedup vs baseline: 2.1150x; 1.0399x over previous
//
#include <hip/hip_runtime.h>
#include <hip/hip_bf16.h>

// PhraseDecoderLayer: B=4,S=1024,D=1024,H=16,HD=64,DFF=4096,MEM=256.
// Round 7: gemm128 with DEPTH-2 register prefetch (CK-style pipeline).
// Register-destined global loads carry across barriers (no vmcnt(0) drain
// needed, unlike global_load_lds), so each tile's loads get ~2 K-steps
// (~1000 cyc) in flight before the commit waits — covers ~900cyc HBM latency.
// Critical for ffn2 (256 blocks = 1 block/CU, no cross-block TLP).
// Attention / kv GEMMs / LN / canon unchanged from passing rounds.

using bf16 = __hip_bfloat16;
typedef __bf16 bf16x8 __attribute__((ext_vector_type(8)));
typedef float f32x4 __attribute__((ext_vector_type(4)));

static constexpr int Bn = 4, Ssz = 1024, Dm = 1024, Hh = 16, HDd = 64, DFFn = 4096, MEMn = 256;

__device__ inline float bf2f(bf16 x) { return __bfloat162float(x); }
__device__ inline bf16 f2bf(float x) { return __float2bfloat16(x); }

// ---------------- dtype detect ----------------
__global__ void detect_kernel(const unsigned* __restrict__ cosw, int* __restrict__ flag) {
  if (threadIdx.x == 0) *flag = (cosw[0] == 0x3F800000u) ? 1 : 0;
}

// ---------------- fused canonicalize: all inputs -> bf16 (+f32 resid for seg0) ----
struct CanonArgs {
  const void* src[23];
  void* dst[23];
  int n[23];  // element count (0 = skip); all counts divisible by 4
};
__global__ __launch_bounds__(256) void canon_all(CanonArgs a, float* __restrict__ resid,
                                                 const int* __restrict__ flagp) {
  const int seg = blockIdx.y;
  const int n4 = a.n[seg] >> 2;
  if (n4 == 0) return;
  const int fl = *flagp;  // wave-uniform
  if (fl) {
    const float4* s = (const float4*)a.src[seg];
    bf16* d = (bf16*)a.dst[seg];
    for (int i = blockIdx.x * 256 + threadIdx.x; i < n4; i += gridDim.x * 256) {
      float4 v = s[i];
      bf16 t[4] = {f2bf(v.x), f2bf(v.y), f2bf(v.z), f2bf(v.w)};
      *reinterpret_cast<unsigned long long*>(d + i * 4) =
          *reinterpret_cast<unsigned long long*>(t);
      if (seg == 0) *reinterpret_cast<float4*>(resid + i * 4) = v;
    }
  } else {
    const unsigned long long* s = (const unsigned long long*)a.src[seg];
    unsigned long long* d = (unsigned long long*)a.dst[seg];
    for (int i = blockIdx.x * 256 + threadIdx.x; i < n4; i += gridDim.x * 256) {
      unsigned long long v = s[i];
      d[i] = v;
      if (seg == 0) {
        const unsigned short* u = reinterpret_cast<const unsigned short*>(&v);
        float4 f;
        f.x = __uint_as_float(((unsigned)u[0]) << 16);
        f.y = __uint_as_float(((unsigned)u[1]) << 16);
        f.z = __uint_as_float(((unsigned)u[2]) << 16);
        f.w = __uint_as_float(((unsigned)u[3]) << 16);
        *reinterpret_cast<float4*>(resid + i * 4) = f;
      }
    }
  }
}

// ---------------- LayerNorm (rows of 1024, fp32 in, bf16 out) ----------------
__global__ __launch_bounds__(256) void ln_kernel(const float* __restrict__ x,
                                                 const bf16* __restrict__ g,
                                                 const bf16* __restrict__ bb,
                                                 bf16* __restrict__ y) {
  const int row = blockIdx.x;
  const float* xr = x + (size_t)row * Dm;
  const int i0 = threadIdx.x * 4;
  float4 v = *reinterpret_cast<const float4*>(xr + i0);
  float s = v.x + v.y + v.z + v.w;
  float ss = v.x * v.x + v.y * v.y + v.z * v.z + v.w * v.w;
#pragma unroll
  for (int o = 32; o > 0; o >>= 1) {
    s += __shfl_down(s, o);
    ss += __shfl_down(ss, o);
  }
  __shared__ float shs[4], shss[4];
  const int wave = threadIdx.x >> 6, lane = threadIdx.x & 63;
  if (lane == 0) { shs[wave] = s; shss[wave] = ss; }
  __syncthreads();
  s = shs[0] + shs[1] + shs[2] + shs[3];
  ss = shss[0] + shss[1] + shss[2] + shss[3];
  const float mu = s * (1.0f / Dm);
  const float var = fmaxf(ss * (1.0f / Dm) - mu * mu, 0.0f);
  const float rs = rsqrtf(var + 1e-5f);
  bf16* yr = y + (size_t)row * Dm + i0;
  float vv[4] = {v.x, v.y, v.z, v.w};
#pragma unroll
  for (int j = 0; j < 4; ++j)
    yr[j] = f2bf((vv[j] - mu) * rs * bf2f(g[i0 + j]) + bf2f(bb[i0 + j]));
}

// ---------------- GEMM 64x64 (round-2 verified; used for M=1024 kv) --------
__global__ __launch_bounds__(256) void gemm_bt(
    const bf16* __restrict__ A, const bf16* __restrict__ W,
    const bf16* __restrict__ bias, bf16* __restrict__ outB, float* __restrict__ outF,
    const float* __restrict__ residIn, float* __restrict__ residOut,
    const int* __restrict__ flagp, int M, int N, int K, int epi) {
  __shared__ bf16 As[64][40];
  __shared__ bf16 Ws[64][40];
  const int tid = threadIdx.x;
  const int m0 = blockIdx.x * 64, n0 = blockIdx.y * 64;
  const int wave = tid >> 6, lane = tid & 63;
  const int wm = wave >> 1, wn = wave & 1;
  const int quad = lane >> 4, m16 = lane & 15;
  const int lr = tid >> 2, lc = (tid & 3) * 8;

  f32x4 acc[2][2] = {};

  const bf16* Ap = A + (size_t)(m0 + lr) * K + lc;
  const bf16* Wp = W + (size_t)(n0 + lr) * K + lc;
  for (int k0 = 0; k0 < K; k0 += 32) {
    float4 av = *reinterpret_cast<const float4*>(Ap + k0);
    float4 wv = *reinterpret_cast<const float4*>(Wp + k0);
    *reinterpret_cast<float4*>(&As[lr][lc]) = av;
    *reinterpret_cast<float4*>(&Ws[lr][lc]) = wv;
    __syncthreads();
    bf16x8 aF[2], bF[2];
#pragma unroll
    for (int t = 0; t < 2; ++t) {
      aF[t] = *reinterpret_cast<const bf16x8*>(&As[wm * 32 + t * 16 + m16][quad * 8]);
      bF[t] = *reinterpret_cast<const bf16x8*>(&Ws[wn * 32 + t * 16 + m16][quad * 8]);
    }
#pragma unroll
    for (int mt = 0; mt < 2; ++mt)
#pragma unroll
      for (int nt = 0; nt < 2; ++nt)
        acc[mt][nt] = __builtin_amdgcn_mfma_f32_16x16x32_bf16(aF[mt], bF[nt], acc[mt][nt], 0, 0, 0);
    __syncthreads();
  }
  const int fl = (epi == 3) ? *flagp : 0;
#pragma unroll
  for (int mt = 0; mt < 2; ++mt) {
#pragma unroll
    for (int nt = 0; nt < 2; ++nt) {
      const int col = n0 + wn * 32 + nt * 16 + m16;
      const float bv = bf2f(bias[col]);
#pragma unroll
      for (int r = 0; r < 4; ++r) {
        const int row = m0 + wm * 32 + mt * 16 + quad * 4 + r;
        const size_t idx = (size_t)row * N + col;
        float v = acc[mt][nt][r] + bv;
        if (epi == 0) {
          outB[idx] = f2bf(v);
        } else if (epi == 1) {
          outB[idx] = f2bf(0.5f * v * (1.0f + erff(v * 0.70710678118654752f)));
        } else if (epi == 2) {
          residOut[idx] = residIn[idx] + v;
        } else {
          const float rr = residIn[idx] + v;
          if (fl) outF[idx] = rr; else outB[idx] = f2bf(rr);
        }
      }
    }
  }
}

// ---------------- GEMM 128x128, depth-2 register pipeline, padded LDS -------
// Stage X holds even tiles, stage Y odd tiles. Commit of tile s waits only
// on loads issued 2 K-steps earlier (vmcnt(4) steady state); loads stay in
// flight across barriers (VGPR destination, no drain required).
__global__ __launch_bounds__(256) void gemm128(
    const bf16* __restrict__ A, const bf16* __restrict__ W,
    const bf16* __restrict__ bias, bf16* __restrict__ outB, float* __restrict__ outF,
    const float* __restrict__ residIn, float* __restrict__ residOut,
    const int* __restrict__ flagp, int M, int N, int K, int epi) {
  __shared__ bf16 As[128][40];
  __shared__ bf16 Ws[128][40];
  const int tid = threadIdx.x;
  const int wave = tid >> 6, lane = tid & 63;
  const int wm = wave >> 1, wn = wave & 1;
  const int quad = lane >> 4, m16 = lane & 15;
  const int m0 = blockIdx.x * 128, n0 = blockIdx.y * 128;

  const int lr = tid >> 2;         // 0..63
  const int lc = (tid & 3) * 8;    // 0,8,16,24
  const bf16* Ap = A + (size_t)(m0 + lr) * K + lc;
  const bf16* Wp = W + (size_t)(n0 + lr) * K + lc;
  const size_t rowOff = (size_t)64 * K;

  f32x4 acc[4][4] = {};

  // prologue: tiles 0 (X) and 1 (Y) into registers
  float4 ax0 = *reinterpret_cast<const float4*>(Ap);
  float4 ax1 = *reinterpret_cast<const float4*>(Ap + rowOff);
  float4 wx0 = *reinterpret_cast<const float4*>(Wp);
  float4 wx1 = *reinterpret_cast<const float4*>(Wp + rowOff);
  float4 ay0 = *reinterpret_cast<const float4*>(Ap + 32);
  float4 ay1 = *reinterpret_cast<const float4*>(Ap + rowOff + 32);
  float4 wy0 = *reinterpret_cast<const float4*>(Wp + 32);
  float4 wy1 = *reinterpret_cast<const float4*>(Wp + rowOff + 32);

  const int nsteps = K >> 5;  // K % 64 == 0 always -> nsteps even
  for (int s = 0; s < nsteps; s += 2) {
    // ---- sub-step A: compute tile s (stage X) ----
    *reinterpret_cast<float4*>(&As[lr][lc]) = ax0;
    *reinterpret_cast<float4*>(&As[64 + lr][lc]) = ax1;
    *reinterpret_cast<float4*>(&Ws[lr][lc]) = wx0;
    *reinterpret_cast<float4*>(&Ws[64 + lr][lc]) = wx1;
    __syncthreads();
    if (s + 2 < nsteps) {
      const int k2 = (s + 2) * 32;
      ax0 = *reinterpret_cast<const float4*>(Ap + k2);
      ax1 = *reinterpret_cast<const float4*>(Ap + rowOff + k2);
      wx0 = *reinterpret_cast<const float4*>(Wp + k2);
      wx1 = *reinterpret_cast<const float4*>(Wp + rowOff + k2);
    }
    {
      bf16x8 aF[4], bF[4];
#pragma unroll
      for (int t = 0; t < 4; ++t) {
        aF[t] = *reinterpret_cast<const bf16x8*>(&As[wm * 64 + t * 16 + m16][quad * 8]);
        bF[t] = *reinterpret_cast<const bf16x8*>(&Ws[wn * 64 + t * 16 + m16][quad * 8]);
      }
#pragma unroll
      for (int mt = 0; mt < 4; ++mt)
#pragma unroll
        for (int nt = 0; nt < 4; ++nt)
          acc[mt][nt] = __builtin_amdgcn_mfma_f32_16x16x32_bf16(aF[mt], bF[nt], acc[mt][nt], 0, 0, 0);
    }
    __syncthreads();
    // ---- sub-step B: compute tile s+1 (stage Y) ----
    *reinterpret_cast<float4*>(&As[lr][lc]) = ay0;
    *reinterpret_cast<float4*>(&As[64 + lr][lc]) = ay1;
    *reinterpret_cast<float4*>(&Ws[lr][lc]) = wy0;
    *reinterpret_cast<float4*>(&Ws[64 + lr][lc]) = wy1;
    __syncthreads();
    if (s + 3 < nsteps) {
      const int k3 = (s + 3) * 32;
      ay0 = *reinterpret_cast<const float4*>(Ap + k3);
      ay1 = *reinterpret_cast<const float4*>(Ap + rowOff + k3);
      wy0 = *reinterpret_cast<const float4*>(Wp + k3);
      wy1 = *reinterpret_cast<const float4*>(Wp + rowOff + k3);
    }
    {
      bf16x8 aF[4], bF[4];
#pragma unroll
      for (int t = 0; t < 4; ++t) {
        aF[t] = *reinterpret_cast<const bf16x8*>(&As[wm * 64 + t * 16 + m16][quad * 8]);
        bF[t] = *reinterpret_cast<const bf16x8*>(&Ws[wn * 64 + t * 16 + m16][quad * 8]);
      }
#pragma unroll
      for (int mt = 0; mt < 4; ++mt)
#pragma unroll
        for (int nt = 0; nt < 4; ++nt)
          acc[mt][nt] = __builtin_amdgcn_mfma_f32_16x16x32_bf16(aF[mt], bF[nt], acc[mt][nt], 0, 0, 0);
    }
    __syncthreads();
  }
  const int fl = (epi == 3) ? *flagp : 0;
  // C/D layout: col = lane&15, row = quad*4 + reg
#pragma unroll
  for (int mt = 0; mt < 4; ++mt) {
#pragma unroll
    for (int nt = 0; nt < 4; ++nt) {
      const int col = n0 + wn * 64 + nt * 16 + m16;
      const float bv = bf2f(bias[col]);
#pragma unroll
      for (int r = 0; r < 4; ++r) {
        const int row = m0 + wm * 64 + mt * 16 + quad * 4 + r;
        const size_t idx = (size_t)row * N + col;
        float v = acc[mt][nt][r] + bv;
        if (epi == 0) {
          outB[idx] = f2bf(v);
        } else if (epi == 1) {
          outB[idx] = f2bf(0.5f * v * (1.0f + erff(v * 0.70710678118654752f)));
        } else if (epi == 2) {
          residOut[idx] = residIn[idx] + v;
        } else {
          const float rr = residIn[idx] + v;
          if (fl) outF[idx] = rr; else outB[idx] = f2bf(rr);
        }
      }
    }
  }
}

// ---------------- RoPE in-place on qkv buffer [4096, 3072] ----------------
__global__ __launch_bounds__(256) void rope_kernel(bf16* __restrict__ qkv,
                                                   const bf16* __restrict__ cosb,
                                                   const bf16* __restrict__ sinb) {
  const int idx = blockIdx.x * 256 + threadIdx.x;  // over 4096*16*32
  const int i = idx & 31;
  const int h = (idx >> 5) & 15;
  const int r = idx >> 9;
  const int s = r & (Ssz - 1);
  const float c = bf2f(cosb[s * 32 + i]);
  const float sn = bf2f(sinb[s * 32 + i]);
  bf16* base = qkv + (size_t)r * (3 * Dm) + h * 64 + 2 * i;
  float x0 = bf2f(base[0]), x1 = bf2f(base[1]);
  base[0] = f2bf(x0 * c - x1 * sn);
  base[1] = f2bf(x0 * sn + x1 * c);
  x0 = bf2f(base[Dm]); x1 = bf2f(base[Dm + 1]);
  base[Dm] = f2bf(x0 * c - x1 * sn);
  base[Dm + 1] = f2bf(x0 * sn + x1 * c);
}

// ---------------- MFMA flash attention (round-3 verified) ----------------
__global__ __launch_bounds__(256) void attn_mfma(
    const bf16* __restrict__ Qb, const bf16* __restrict__ Kb, const bf16* __restrict__ Vb,
    bf16* __restrict__ Ob, int qStride, int kvStride, int kvLen, int causal, float scale) {
  __shared__ bf16 Ks[64][72];
  __shared__ bf16 Vt[64][72];
  __shared__ bf16 Ps[64][72];
  const int tid = threadIdx.x;
  const int wave = tid >> 6, lane = tid & 63;
  const int quad = lane >> 4, m16 = lane & 15;
  const int b = blockIdx.z, h = blockIdx.y;
  const int q0 = blockIdx.x * 64;
  const int sr = tid >> 2, sc = (tid & 3) * 16;

  {
    const bf16* qp = Qb + (size_t)(b * Ssz + q0 + sr) * qStride + h * 64 + sc;
    float4 a = reinterpret_cast<const float4*>(qp)[0];
    float4 bb2 = reinterpret_cast<const float4*>(qp)[1];
    *reinterpret_cast<float4*>(&Ps[sr][sc]) = a;
    *reinterpret_cast<float4*>(&Ps[sr][sc + 8]) = bb2;
  }
  __syncthreads();
  bf16x8 qf[2];
  qf[0] = *reinterpret_cast<const bf16x8*>(&Ps[wave * 16 + m16][quad * 8]);
  qf[1] = *reinterpret_cast<const bf16x8*>(&Ps[wave * 16 + m16][32 + quad * 8]);

  f32x4 oacc[4] = {};
  float mrow[4], lrow[4];
#pragma unroll
  for (int r = 0; r < 4; ++r) { mrow[r] = -30000.0f; lrow[r] = 0.0f; }

  const int nk = causal ? (q0 + 64) : kvLen;
  for (int kt = 0; kt < nk; kt += 64) {
    {
      const bf16* kp = Kb + (size_t)(b * kvLen + kt + sr) * kvStride + h * 64 + sc;
      float4 k1 = reinterpret_cast<const float4*>(kp)[0];
      float4 k2 = reinterpret_cast<const float4*>(kp)[1];
      *reinterpret_cast<float4*>(&Ks[sr][sc]) = k1;
      *reinterpret_cast<float4*>(&Ks[sr][sc + 8]) = k2;
      const bf16* vp = Vb + (size_t)(b * kvLen + kt + sr) * kvStride + h * 64 + sc;
      float4 v1 = reinterpret_cast<const float4*>(vp)[0];
      float4 v2 = reinterpret_cast<const float4*>(vp)[1];
      const bf16* tv1 = reinterpret_cast<const bf16*>(&v1);
      const bf16* tv2 = reinterpret_cast<const bf16*>(&v2);
#pragma unroll
      for (int j = 0; j < 8; ++j) {
        Vt[sc + j][sr] = tv1[j];
        Vt[sc + 8 + j][sr] = tv2[j];
      }
    }
    __syncthreads();

    f32x4 sacc[4] = {};
#pragma unroll
    for (int nt = 0; nt < 4; ++nt) {
      bf16x8 kf0 = *reinterpret_cast<const bf16x8*>(&Ks[nt * 16 + m16][quad * 8]);
      bf16x8 kf1 = *reinterpret_cast<const bf16x8*>(&Ks[nt * 16 + m16][32 + quad * 8]);
      sacc[nt] = __builtin_amdgcn_mfma_f32_16x16x32_bf16(qf[0], kf0, sacc[nt], 0, 0, 0);
      sacc[nt] = __builtin_amdgcn_mfma_f32_16x16x32_bf16(qf[1], kf1, sacc[nt], 0, 0, 0);
    }
    const bool dmask = (causal != 0) && (kt == q0);
#pragma unroll
    for (int nt = 0; nt < 4; ++nt) {
#pragma unroll
      for (int r = 0; r < 4; ++r) {
        float s = sacc[nt][r] * scale;
        if (dmask && (nt * 16 + m16 > wave * 16 + quad * 4 + r)) s = -30000.0f;
        sacc[nt][r] = s;
      }
    }

#pragma unroll
    for (int r = 0; r < 4; ++r) {
      float mx = fmaxf(fmaxf(sacc[0][r], sacc[1][r]), fmaxf(sacc[2][r], sacc[3][r]));
#pragma unroll
      for (int off = 1; off < 16; off <<= 1) mx = fmaxf(mx, __shfl_xor(mx, off));
      const float mn = fmaxf(mrow[r], mx);
      const float corr = __expf(mrow[r] - mn);
      mrow[r] = mn;
      float psum = 0.0f;
#pragma unroll
      for (int nt = 0; nt < 4; ++nt) {
        const float p = __expf(sacc[nt][r] - mn);
        sacc[nt][r] = p;
        psum += p;
      }
#pragma unroll
      for (int off = 1; off < 16; off <<= 1) psum += __shfl_xor(psum, off);
      lrow[r] = lrow[r] * corr + psum;
#pragma unroll
      for (int nt = 0; nt < 4; ++nt) oacc[nt][r] *= corr;
#pragma unroll
      for (int nt = 0; nt < 4; ++nt)
        Ps[wave * 16 + quad * 4 + r][nt * 16 + m16] = f2bf(sacc[nt][r]);
    }
    bf16x8 pf0 = *reinterpret_cast<const bf16x8*>(&Ps[wave * 16 + m16][quad * 8]);
    bf16x8 pf1 = *reinterpret_cast<const bf16x8*>(&Ps[wave * 16 + m16][32 + quad * 8]);
#pragma unroll
    for (int nt = 0; nt < 4; ++nt) {
      bf16x8 vf0 = *reinterpret_cast<const bf16x8*>(&Vt[nt * 16 + m16][quad * 8]);
      bf16x8 vf1 = *reinterpret_cast<const bf16x8*>(&Vt[nt * 16 + m16][32 + quad * 8]);
      oacc[nt] = __builtin_amdgcn_mfma_f32_16x16x32_bf16(pf0, vf0, oacc[nt], 0, 0, 0);
      oacc[nt] = __builtin_amdgcn_mfma_f32_16x16x32_bf16(pf1, vf1, oacc[nt], 0, 0, 0);
    }
    __syncthreads();
  }

  float inv[4];
#pragma unroll
  for (int r = 0; r < 4; ++r) inv[r] = 1.0f / lrow[r];
#pragma unroll
  for (int r = 0; r < 4; ++r) {
    bf16* op = Ob + (size_t)(b * Ssz + q0 + wave * 16 + quad * 4 + r) * Dm + h * 64 + m16;
#pragma unroll
    for (int nt = 0; nt < 4; ++nt) op[nt * 16] = f2bf(oacc[nt][r] * inv[r]);
  }
}

extern "C" void kernel_launch(void* const* d_in, const int* in_sizes, int n_in,
                              void* d_out, int out_size, void* d_ws, size_t ws_size,
                              hipStream_t stream) {
  char* ws = (char*)d_ws;
  int* flagp   = (int*)ws;                          // [0,1MB) control
  float* resid = (float*)(ws + (1ull << 20));       // 16MB fp32 residual
  bf16* xln    = (bf16*)(ws + (17ull << 20));       // 8MB LN output
  bf16* aout   = (bf16*)(ws + (25ull << 20));       // 8MB attn out
  bf16* big    = (bf16*)(ws + (33ull << 20));       // 32MB: qkv | qb | ffn1
  size_t off   = (65ull << 20);                     // canonical bf16 inputs

  detect_kernel<<<1, 64, 0, stream>>>((const unsigned*)d_in[3], flagp);

  CanonArgs ca;
  bf16* c[23];
  for (int i = 0; i < 23; ++i) {
    if (i == 2) { c[i] = nullptr; ca.src[i] = d_in[i]; ca.dst[i] = nullptr; ca.n[i] = 0; continue; }
    c[i] = (bf16*)(ws + off);
    const int n = in_sizes[i];
    off += ((size_t)n * 2 + 255) & ~(size_t)255;
    ca.src[i] = d_in[i];
    ca.dst[i] = c[i];
    ca.n[i] = n;
  }
  canon_all<<<dim3(256, 23), 256, 0, stream>>>(ca, resid, flagp);

  const bf16 *memory = c[1], *rope_cos = c[3], *rope_sin = c[4];
  const bf16 *qkv_w = c[5], *qkv_b = c[6], *out_w = c[7], *out_b = c[8];
  const bf16 *ca_in_w = c[9], *ca_in_b = c[10], *ca_out_w = c[11], *ca_out_b = c[12];
  const bf16 *ffn_w1 = c[13], *ffn_b1 = c[14], *ffn_w2 = c[15], *ffn_b2 = c[16];
  const bf16 *ln1_g = c[17], *ln1_b = c[18], *ln2_g = c[19], *ln2_b = c[20];
  const bf16 *ln3_g = c[21], *ln3_b = c[22];

  bf16* qb = big;
  bf16* kb = (bf16*)(ws + (41ull << 20));
  bf16* vb = (bf16*)(ws + (43ull << 20));
  bf16* outB = (bf16*)d_out;
  float* outF = (float*)d_out;

  const int ROWS = Bn * Ssz;   // 4096
  const float scale = 0.125f;  // 1/sqrt(64)

  // ---- self attention ----
  ln_kernel<<<ROWS, 256, 0, stream>>>(resid, ln1_g, ln1_b, xln);
  gemm128<<<dim3(ROWS / 128, (3 * Dm) / 128), 256, 0, stream>>>(
      xln, qkv_w, qkv_b, big, nullptr, nullptr, nullptr, nullptr, ROWS, 3 * Dm, Dm, 0);
  rope_kernel<<<(ROWS * Hh * (HDd / 2)) / 256, 256, 0, stream>>>(big, rope_cos, rope_sin);
  attn_mfma<<<dim3(Ssz / 64, Hh, Bn), 256, 0, stream>>>(
      big, big + Dm, big + 2 * Dm, aout, 3 * Dm, 3 * Dm, Ssz, 1, scale);
  gemm128<<<dim3(ROWS / 128, Dm / 128), 256, 0, stream>>>(
      aout, out_w, out_b, nullptr, nullptr, resid, resid, nullptr, ROWS, Dm, Dm, 2);

  // ---- cross attention ----
  ln_kernel<<<ROWS, 256, 0, stream>>>(resid, ln2_g, ln2_b, xln);
  gemm128<<<dim3(ROWS / 128, Dm / 128), 256, 0, stream>>>(
      xln, ca_in_w, ca_in_b, qb, nullptr, nullptr, nullptr, nullptr, ROWS, Dm, Dm, 0);
  gemm_bt<<<dim3((Bn * MEMn) / 64, Dm / 64), 256, 0, stream>>>(
      memory, ca_in_w + (size_t)Dm * Dm, ca_in_b + Dm, kb, nullptr, nullptr, nullptr, nullptr,
      Bn * MEMn, Dm, Dm, 0);
  gemm_bt<<<dim3((Bn * MEMn) / 64, Dm / 64), 256, 0, stream>>>(
      memory, ca_in_w + (size_t)2 * Dm * Dm, ca_in_b + 2 * Dm, vb, nullptr, nullptr, nullptr, nullptr,
      Bn * MEMn, Dm, Dm, 0);
  attn_mfma<<<dim3(Ssz / 64, Hh, Bn), 256, 0, stream>>>(
      qb, kb, vb, aout, Dm, Dm, MEMn, 0, scale);
  gemm128<<<dim3(ROWS / 128, Dm / 128), 256, 0, stream>>>(
      aout, ca_out_w, ca_out_b, nullptr, nullptr, resid, resid, nullptr, ROWS, Dm, Dm, 2);

  // ---- FFN ----
  ln_kernel<<<ROWS, 256, 0, stream>>>(resid, ln3_g, ln3_b, xln);
  gemm128<<<dim3(ROWS / 128, DFFn / 128), 256, 0, stream>>>(
      xln, ffn_w1, ffn_b1, big, nullptr, nullptr, nullptr, nullptr, ROWS, DFFn, Dm, 1);
  gemm128<<<dim3(ROWS / 128, Dm / 128), 256, 0, stream>>>(
      big, ffn_w2, ffn_b2, outB, outF, resid, nullptr, flagp, ROWS, Dm, DFFn, 3);
}